// Round 6
// baseline (599.210 us; speedup 1.0000x reference)
//
#include <hip/hip_runtime.h>
#include <math.h>

typedef unsigned short u16;
typedef unsigned int u32;
typedef short bf16x8 __attribute__((ext_vector_type(8)));
typedef unsigned short u16x8 __attribute__((ext_vector_type(8)));
typedef float f32x4 __attribute__((ext_vector_type(4)));

#define DEV static __device__ __forceinline__

#define BB 256
#define NN 181
#define DD 512
#define HH 8
#define DKk 64
#define NPAD 192
#define MTOT (BB*NN)          // 46336
#define QKV_ELEMS (23724032u) // B*H*N*64
#define WS_NEEDED 196384768ull

DEV u16 f2bf(float f){
  u32 u = __float_as_uint(f);
  u32 r = (u + 0x7FFFu + ((u >> 16) & 1u)) >> 16;
  return (u16)r;
}
DEV float bf2f(u16 h){ return __uint_as_float(((u32)h) << 16); }
DEV bf16x8 as_bf(u16x8 v){ return __builtin_bit_cast(bf16x8, v); }

DEV void gl_lds16(const u16* g, u16* l){
  __builtin_amdgcn_global_load_lds(
      (const __attribute__((address_space(1))) unsigned int*)g,
      (__attribute__((address_space(3))) unsigned int*)l, 16, 0, 0);
}

// ---------------- unified prep: casts + bias table + bias concat ----------------
DEV void cast8(const float* __restrict__ src, u16* __restrict__ dst, int u){
  const float4* p = reinterpret_cast<const float4*>(src + (size_t)u*8);
  float4 a = p[0], b = p[1];
  u16x8 o;
  o[0]=f2bf(a.x); o[1]=f2bf(a.y); o[2]=f2bf(a.z); o[3]=f2bf(a.w);
  o[4]=f2bf(b.x); o[5]=f2bf(b.y); o[6]=f2bf(b.z); o[7]=f2bf(b.w);
  *reinterpret_cast<u16x8*>(dst + (size_t)u*8) = o;
}

#define SEG_X  2965504
#define SEG_Q  2998272
#define SEG_K  3031040
#define SEG_V  3063808
#define SEG_O  3096576
#define SEG_W1 3227648
#define SEG_W2 3358720
#define SEG_BI 3367936
#define SEG_BC 3368128

__global__ __launch_bounds__(256) void prep_kernel(
    const float* __restrict__ x,  const float* __restrict__ Wq,
    const float* __restrict__ Wk, const float* __restrict__ Wv,
    const float* __restrict__ Wo, const float* __restrict__ w1,
    const float* __restrict__ w2, const float* __restrict__ bq,
    const float* __restrict__ bk, const float* __restrict__ bv,
    const int* __restrict__ mask,
    u16* __restrict__ xb, u16* __restrict__ wqkv, u16* __restrict__ wo_b,
    u16* __restrict__ w1_b, u16* __restrict__ w2_b,
    float* __restrict__ biasA, float* __restrict__ bqkv)
{
  int u = blockIdx.x*256 + threadIdx.x;
  if (u < SEG_X)  { cast8(x,  xb,            u);          return; }
  if (u < SEG_Q)  { cast8(Wq, wqkv,          u - SEG_X);  return; }
  if (u < SEG_K)  { cast8(Wk, wqkv + 262144, u - SEG_Q);  return; }
  if (u < SEG_V)  { cast8(Wv, wqkv + 524288, u - SEG_K);  return; }
  if (u < SEG_O)  { cast8(Wo, wo_b,          u - SEG_V);  return; }
  if (u < SEG_W1) { cast8(w1, w1_b,          u - SEG_O);  return; }
  if (u < SEG_W2) { cast8(w2, w2_b,          u - SEG_W1); return; }
  if (u < SEG_BI) {
    int base = (u - SEG_W2)*8;
    #pragma unroll
    for (int j=0;j<8;++j){
      int idx = base + j;
      int g = idx / (NPAD*NPAD);
      int rem = idx % (NPAD*NPAD);
      int q = rem / NPAD, k = rem % NPAD;
      float v;
      if (k >= NN) v = -INFINITY;
      else if (q >= NN) v = 0.f;
      else {
        bool qv = q < 121, kv = k < 121;
        bool allowed = (g == 0) ? (qv != kv) : (qv == kv);
        if (!allowed) v = -INFINITY;
        else {
          int mb = (g == 0 && !qv) ? mask[k*NN + q] : mask[q*NN + k];
          v = mb ? -1e9f : 0.f;
        }
      }
      biasA[idx] = v;
    }
    return;
  }
  if (u < SEG_BC) {
    int base = (u - SEG_BI)*8;
    #pragma unroll
    for (int j=0;j<8;++j){
      int e = base + j;
      bqkv[e] = (e < 512) ? bq[e] : (e < 1024) ? bk[e-512] : bv[e-1024];
    }
    return;
  }
}

// ================= 256x256 8-phase GEMM, C = A(MxK) * B(NxK)^T =================
// 512 thr = 8 waves (2M x 4N), per-wave output 128x64, BK=64, dbuf LDS 128KB,
// st-swizzled slots (r3/r5-verified, 0 bank conflicts), counted vmcnt(4),
// setprio, m204 bijective XCD remap (nt-fastest).
// EPI 0: QKV scatter (+0.125 Q); 1: +bias+resf(f32); 2: +bias+relu;
// EPI 4: raw->bf16 (partial);    5: +bias+bf2f(resb)+bf2f(res2)
#define STAGE(SB, SO, SH, KT) do { \
    int kt_ = (KT); if (kt_ >= ntiles) kt_ = 0; \
    const int ld_ = (SO) == 0 ? lda : ldb; \
    const u16* s_ = ((SO) == 0 ? stA : stB) + (size_t)(SH)*128*ld_ + (size_t)kt_*64; \
    gl_lds16(s_, &ldsT[SB][SO][SH][wave*512]); \
    gl_lds16(s_ + (size_t)64*ld_, &ldsT[SB][SO][SH][wave*512 + 4096]); \
  } while(0)

#define PHASE(CB, MH, NH, SB, SO, SH, KT, VM) do { \
    bf16x8 af_[4][2], bg_[2][2]; \
    const u16* ap_ = &ldsT[CB][0][MH][0] + aRdBase; \
    const u16* bp_ = &ldsT[CB][1][NH][0] + bRdBase; \
    _Pragma("unroll") for (int m_=0; m_<4; ++m_) \
      _Pragma("unroll") for (int k_=0; k_<2; ++k_) \
        af_[m_][k_] = *reinterpret_cast<const bf16x8*>(ap_ + m_*2048 + k_*512); \
    _Pragma("unroll") for (int n_=0; n_<2; ++n_) \
      _Pragma("unroll") for (int k_=0; k_<2; ++k_) \
        bg_[n_][k_] = *reinterpret_cast<const bf16x8*>(bp_ + n_*4096 + k_*512); \
    STAGE(SB, SO, SH, KT); \
    if (VM) asm volatile("s_waitcnt vmcnt(4)" ::: "memory"); \
    __builtin_amdgcn_sched_barrier(0); \
    __builtin_amdgcn_s_barrier(); \
    __builtin_amdgcn_sched_barrier(0); \
    __builtin_amdgcn_s_setprio(1); \
    _Pragma("unroll") for (int m_=0; m_<4; ++m_) \
      _Pragma("unroll") for (int n_=0; n_<2; ++n_) \
        _Pragma("unroll") for (int k_=0; k_<2; ++k_) \
          acc[(MH)*4+m_][(NH)*2+n_] = __builtin_amdgcn_mfma_f32_16x16x32_bf16( \
              af_[m_][k_], bg_[n_][k_], acc[(MH)*4+m_][(NH)*2+n_], 0,0,0); \
    __builtin_amdgcn_s_setprio(0); \
    __builtin_amdgcn_sched_barrier(0); \
    __builtin_amdgcn_s_barrier(); \
    __builtin_amdgcn_sched_barrier(0); \
  } while(0)

template<int EPI>
__global__ __launch_bounds__(512) void gemm8(
    const u16* __restrict__ A, const u16* __restrict__ Bw,
    int K, int N, int lda, int ldb,
    const float* __restrict__ bias,
    u16* __restrict__ outb,
    const float* __restrict__ resf,
    const u16* __restrict__ resb,
    const u16* __restrict__ res2)
{
  __shared__ u16 ldsT[2][2][2][8192];   // [buf][A/B][half][128x64] 128 KiB
  const int tid = threadIdx.x, lane = tid & 63, wave = tid >> 6;
  const int lo = lane & 15, hi = lane >> 4;
  const int wm = wave >> 2, wn = wave & 3;

  // m204 bijective XCD remap, nt-fastest ids (nwg need not be %8)
  const int nwg = gridDim.x * gridDim.y;
  const int bid = blockIdx.x + gridDim.x * blockIdx.y;
  const int q8 = nwg >> 3, r8 = nwg & 7;
  const int xcd = bid & 7, j8 = bid >> 3;
  const int wgid = (xcd < r8 ? xcd*(q8+1) : r8*(q8+1) + (xcd-r8)*q8) + j8;
  const int ntb = wgid % gridDim.x, mt = wgid / gridDim.x;
  const int ntiles = K >> 6, niter = ntiles >> 1;

  // staging: thread covers physical LDS bytes P = tid*16 (+ j*8192);
  // inverse subtile swizzle -> logical (row pr, col pc) of the half-tile
  const int pr = ((tid >> 7) << 4) | ((tid >> 2) & 15);
  const int pc = (((tid >> 6) & 1) << 5) | (((tid & 3) * 8) ^ (((tid >> 5) & 1) << 4));
  const u16* stA = A  + (size_t)(mt*256 + pr) * lda + pc;
  const u16* stB = Bw + (size_t)(ntb*256 + pr) * ldb + pc;
  // swizzled fragment-read lane base (elements)
  const int aRdBase = wm*1024 + lo*32 + ((hi*8) ^ ((lo & 8) << 1));
  const int bRdBase = wn*1024 + lo*32 + ((hi*8) ^ ((lo & 8) << 1));

  f32x4 acc[8][4];
  #pragma unroll
  for (int f=0; f<8; ++f)
    #pragma unroll
    for (int n=0; n<4; ++n) acc[f][n] = f32x4{0.f,0.f,0.f,0.f};

  // prologue: tile0 all 4 halves + tile1 A0,B0 (12 loads), wait 8 landed
  STAGE(0,0,0, 0); STAGE(0,1,0, 0); STAGE(0,0,1, 0); STAGE(0,1,1, 0);
  STAGE(1,0,0, 1); STAGE(1,1,0, 1);
  asm volatile("s_waitcnt vmcnt(4)" ::: "memory");
  __builtin_amdgcn_sched_barrier(0);
  __builtin_amdgcn_s_barrier();
  __builtin_amdgcn_sched_barrier(0);

  for (int i = 0; i < niter; ++i){
    const int v1 = 2*i+1, u2 = 2*i+2, v2 = 2*i+3;
    PHASE(0,0,0, 1,0,1, v1, 0);   // compute u(0,0); stage A1(v)
    PHASE(0,0,1, 1,1,1, v1, 0);   // u(0,1); B1(v)
    PHASE(0,1,0, 0,0,0, u2, 0);   // u(1,0); A0(u+2)
    PHASE(0,1,1, 0,1,0, u2, 1);   // u(1,1); B0(u+2); vmcnt
    PHASE(1,0,0, 0,0,1, u2, 0);   // v(0,0); A1(u+2)
    PHASE(1,0,1, 0,1,1, u2, 0);   // v(0,1); B1(u+2)
    PHASE(1,1,0, 1,0,0, v2, 0);   // v(1,0); A0(v+2)
    PHASE(1,1,1, 1,1,0, v2, 1);   // v(1,1); B0(v+2); vmcnt
  }
  asm volatile("s_waitcnt vmcnt(0)" ::: "memory");

  // epilogue: row = mt*256 + wm*16 + f*32 + hi*4 + rg; col = ntb*256 + wn*16 + n*64 + lo
  float bv[4];
  #pragma unroll
  for (int n=0; n<4; ++n) bv[n] = bias[ntb*256 + wn*16 + n*64 + lo];
  #pragma unroll
  for (int f=0; f<8; ++f){
    #pragma unroll
    for (int rg=0; rg<4; ++rg){
      const int row = mt*256 + wm*16 + f*32 + hi*4 + rg;
      if constexpr (EPI == 0){
        const int bi = row / NN, ni = row - bi*NN;
        #pragma unroll
        for (int n=0; n<4; ++n){
          const int gcol = ntb*256 + wn*16 + n*64 + lo;
          float v = acc[f][n][rg] + bv[n];
          int which = gcol >> 9;
          int hh = (gcol >> 6) & 7;
          int d  = gcol & 63;
          if (which == 0) v *= 0.125f;
          outb[(size_t)which*QKV_ELEMS + (((size_t)bi*HH + hh)*NN + ni)*DKk + d] = f2bf(v);
        }
      } else {
        #pragma unroll
        for (int n=0; n<4; ++n){
          const int gcol = ntb*256 + wn*16 + n*64 + lo;
          float v = acc[f][n][rg];
          if constexpr (EPI == 1){
            v += bv[n] + resf[(size_t)row*N + gcol];
          } else if constexpr (EPI == 2){
            v = fmaxf(v + bv[n], 0.f);
          } else if constexpr (EPI == 5){
            v += bv[n] + bf2f(resb[(size_t)row*N + gcol]) + bf2f(res2[(size_t)row*N + gcol]);
          }
          outb[(size_t)row*N + gcol] = f2bf(v);
        }
      }
    }
  }
}

// ---------------- fused segment attention (unchanged, verified r2-r5) ----------------
__global__ __launch_bounds__(256) void attn_kernel(
    const u16* __restrict__ Qg, const u16* __restrict__ Kg, const u16* __restrict__ Vg,
    const float* __restrict__ biasA, u16* __restrict__ ctx)
{
  __shared__ u16 Kb[NPAD*72];
  __shared__ u16 Vt[64*200];
  __shared__ u16 Pl[4*16*200];
  const int tid = threadIdx.x, lane = tid & 63, wave = tid >> 6;
  const int lo = lane & 15, hi = lane >> 4;
  const int bh = blockIdx.x;
  const int h = bh & 7, g = h >> 2, b = bh >> 3;
  const size_t base = (size_t)bh * NN * DKk;

  #pragma unroll
  for (int it=0; it<6; ++it){
    int row = it*32 + (tid >> 3);
    int cb = (tid & 7)*8;
    u16x8 val = {0,0,0,0,0,0,0,0};
    if (row < NN) val = *reinterpret_cast<const u16x8*>(Kg + base + (size_t)row*DKk + cb);
    *reinterpret_cast<u16x8*>(&Kb[row*72 + cb]) = val;
  }
  #pragma unroll
  for (int it=0; it<6; ++it){
    int row = it*32 + (tid >> 3);
    int cb = (tid & 7)*8;
    u16x8 val = {0,0,0,0,0,0,0,0};
    if (row < NN) val = *reinterpret_cast<const u16x8*>(Vg + base + (size_t)row*DKk + cb);
    *reinterpret_cast<u16x8*>(&Pl[row*64 + cb]) = val;
  }
  __syncthreads();
  #pragma unroll
  for (int j=0;j<6;++j){
    int task = j*256 + tid;
    int d = task & 63;
    int nc = task >> 6;
    u16x8 tv;
    #pragma unroll
    for (int i=0;i<8;++i) tv[i] = Pl[(nc*8+i)*64 + d];
    *reinterpret_cast<u16x8*>(&Vt[d*200 + nc*8]) = tv;
  }
  __syncthreads();

  u16* pw = Pl + wave*16*200;

  for (int rb = wave; rb < 12; rb += 4){
    const int q0 = rb*16;
    const int qrow = q0 + lo;
    bf16x8 qa[2];
    #pragma unroll
    for (int kk=0;kk<2;++kk){
      u16x8 val = {0,0,0,0,0,0,0,0};
      if (qrow < NN) val = *reinterpret_cast<const u16x8*>(Qg + base + (size_t)qrow*DKk + kk*32 + hi*8);
      qa[kk] = as_bf(val);
    }
    f32x4 s[12];
    #pragma unroll
    for (int c=0;c<12;++c){
      f32x4 a = f32x4{0.f,0.f,0.f,0.f};
      #pragma unroll
      for (int kk=0;kk<2;++kk){
        bf16x8 kb = *reinterpret_cast<const bf16x8*>(&Kb[(c*16+lo)*72 + kk*32 + hi*8]);
        a = __builtin_amdgcn_mfma_f32_16x16x32_bf16(qa[kk], kb, a, 0,0,0);
      }
      s[c] = a;
    }
    const float* brow = biasA + ((size_t)g*NPAD + q0 + hi*4)*NPAD + lo;
    #pragma unroll
    for (int r=0;r<4;++r)
      #pragma unroll
      for (int c=0;c<12;++c)
        s[c][r] += brow[r*NPAD + c*16];
    float inv[4];
    #pragma unroll
    for (int r=0;r<4;++r){
      float m = s[0][r];
      #pragma unroll
      for (int c=1;c<12;++c) m = fmaxf(m, s[c][r]);
      #pragma unroll
      for (int off=1; off<16; off<<=1) m = fmaxf(m, __shfl_xor(m, off, 64));
      float t = 0.f;
      #pragma unroll
      for (int c=0;c<12;++c){ float e = __expf(s[c][r] - m); s[c][r] = e; t += e; }
      #pragma unroll
      for (int off=1; off<16; off<<=1) t += __shfl_xor(t, off, 64);
      inv[r] = 1.0f / t;
    }
    #pragma unroll
    for (int c=0;c<12;++c)
      #pragma unroll
      for (int r=0;r<4;++r)
        pw[(hi*4+r)*200 + c*16 + lo] = f2bf(s[c][r] * inv[r]);
    asm volatile("s_waitcnt lgkmcnt(0)" ::: "memory");
    __builtin_amdgcn_sched_barrier(0);
    bf16x8 pa[6];
    #pragma unroll
    for (int c6=0;c6<6;++c6)
      pa[c6] = *reinterpret_cast<const bf16x8*>(&pw[lo*200 + c6*32 + hi*8]);
    #pragma unroll
    for (int dt=0;dt<4;++dt){
      f32x4 a = f32x4{0.f,0.f,0.f,0.f};
      #pragma unroll
      for (int c6=0;c6<6;++c6){
        bf16x8 vb = *reinterpret_cast<const bf16x8*>(&Vt[(dt*16+lo)*200 + c6*32 + hi*8]);
        a = __builtin_amdgcn_mfma_f32_16x16x32_bf16(pa[c6], vb, a, 0,0,0);
      }
      #pragma unroll
      for (int r=0;r<4;++r){
        int q = q0 + hi*4 + r;
        if (q < NN)
          ctx[((size_t)b*NN + q)*DD + h*DKk + dt*16 + lo] = f2bf(a[r]);
      }
    }
  }
}

// ---------------- LayerNorm over D=512, one wave per row ----------------
template<int OUTF32>
__global__ __launch_bounds__(256) void ln_kernel(
    const u16* __restrict__ in, const float* __restrict__ gamma,
    const float* __restrict__ beta, void* __restrict__ outp)
{
  const int row = blockIdx.x*4 + (threadIdx.x >> 6);
  const int lane = threadIdx.x & 63;
  u16x8 rv = *reinterpret_cast<const u16x8*>(in + (size_t)row*512 + lane*8);
  float x[8]; float s = 0.f, s2 = 0.f;
  #pragma unroll
  for (int i=0;i<8;++i){ x[i] = bf2f(rv[i]); s += x[i]; s2 += x[i]*x[i]; }
  #pragma unroll
  for (int off=32; off>=1; off>>=1){ s += __shfl_xor(s, off, 64); s2 += __shfl_xor(s2, off, 64); }
  const float mu = s * (1.f/512.f);
  const float var = s2 * (1.f/512.f) - mu*mu;
  const float rstd = rsqrtf(var + 1e-5f);
  float4 ga = *reinterpret_cast<const float4*>(gamma + lane*8);
  float4 gb = *reinterpret_cast<const float4*>(gamma + lane*8 + 4);
  float4 ba = *reinterpret_cast<const float4*>(beta + lane*8);
  float4 bb = *reinterpret_cast<const float4*>(beta + lane*8 + 4);
  float gg[8] = {ga.x,ga.y,ga.z,ga.w,gb.x,gb.y,gb.z,gb.w};
  float bt[8] = {ba.x,ba.y,ba.z,ba.w,bb.x,bb.y,bb.z,bb.w};
  if constexpr (OUTF32){
    float o[8];
    #pragma unroll
    for (int i=0;i<8;++i) o[i] = (x[i]-mu)*rstd*gg[i] + bt[i];
    float4* op = reinterpret_cast<float4*>((float*)outp + (size_t)row*512 + lane*8);
    op[0] = make_float4(o[0],o[1],o[2],o[3]);
    op[1] = make_float4(o[4],o[5],o[6],o[7]);
  } else {
    u16x8 o;
    #pragma unroll
    for (int i=0;i<8;++i) o[i] = f2bf((x[i]-mu)*rstd*gg[i] + bt[i]);
    *reinterpret_cast<u16x8*>((u16*)outp + (size_t)row*512 + lane*8) = o;
  }
}

// ---------------- launch ----------------
// ws map (total 196,384,768 B) — identical to r4/r5:
//   [0        ..  2097152) w1_b     [2097152 ..  4194304) w2_b
//   [4194304  ..  5767168) wqkv     [5767168 ..  6291456) wo_b
//   [6291456  ..  6586368) biasA    [6586368 ..  6592512) bqkv
//   [6592512  .. 54040576) xb  : x bf16 -> ctx
//   [54040576 ..101488640) qbuf: Q -> r1
//   [101488640..148936704) kbuf: K -> h
//   [148936704..196384768) vbuf: V -> FF2a partial -> s2
//   ffbuf = ws+4194304 (46336x1024 bf16 ends 99,090,432 < kbuf)
extern "C" void kernel_launch(void* const* d_in, const int* in_sizes, int n_in,
                              void* d_out, int out_size, void* d_ws, size_t ws_size,
                              hipStream_t stream)
{
  if (ws_size < WS_NEEDED) return;

  const float* x   = (const float*)d_in[0];
  const int*   mask= (const int*)  d_in[1];
  const float* Wq  = (const float*)d_in[2];
  const float* bq  = (const float*)d_in[3];
  const float* Wk  = (const float*)d_in[4];
  const float* bk  = (const float*)d_in[5];
  const float* Wv  = (const float*)d_in[6];
  const float* bv  = (const float*)d_in[7];
  const float* Wo  = (const float*)d_in[8];
  const float* bo  = (const float*)d_in[9];
  const float* w1  = (const float*)d_in[10];
  const float* b1  = (const float*)d_in[11];
  const float* w2  = (const float*)d_in[12];
  const float* b2  = (const float*)d_in[13];
  const float* g1  = (const float*)d_in[14];
  const float* be1 = (const float*)d_in[15];
  const float* g2  = (const float*)d_in[16];
  const float* be2 = (const float*)d_in[17];

  char* ws = (char*)d_ws;
  u16*   w1_b  = (u16*)  (ws + 0);
  u16*   w2_b  = (u16*)  (ws + 2097152);
  u16*   wqkv  = (u16*)  (ws + 4194304);
  u16*   wo_b  = (u16*)  (ws + 5767168);
  float* biasA = (float*)(ws + 6291456);
  float* bqkv  = (float*)(ws + 6586368);
  u16*   xb    = (u16*)  (ws + 6592512);
  u16*   qbuf  = (u16*)  (ws + 54040576);
  u16*   kbuf  = qbuf + QKV_ELEMS;
  u16*   vbuf  = qbuf + 2*QKV_ELEMS;
  u16*   ffbuf = (u16*)  (ws + 4194304);

  // one fused prep launch
  prep_kernel<<<13157, 256, 0, stream>>>(x, Wq, Wk, Wv, Wo, w1, w2, bq, bk, bv,
                                         mask, xb, wqkv, wo_b, w1_b, w2_b, biasA, bqkv);

  // QKV projection (scatter to [B,H,N,64] bf16, Q scaled by 1/8)
  gemm8<0><<<dim3(6,181), 512, 0, stream>>>(xb, wqkv, 512, 1536, 512, 512,
                                            bqkv, qbuf, nullptr, nullptr, nullptr);
  // fused segment attention -> ctx (xb region)
  attn_kernel<<<2048, 256, 0, stream>>>(qbuf, kbuf, vbuf, biasA, xb);
  // Wo projection + bo + x residual -> r1 (qbuf)
  gemm8<1><<<dim3(2,181), 512, 0, stream>>>(xb, wo_b, 512, 512, 512, 512,
                                            bo, qbuf, x, nullptr, nullptr);
  // LN1 -> h (kbuf)
  ln_kernel<0><<<11584, 256, 0, stream>>>(qbuf, g1, be1, kbuf);
  // FF1a: h x w1[0:1024,:] + relu -> ffbuf
  gemm8<2><<<dim3(4,181), 512, 0, stream>>>(kbuf, w1_b, 512, 1024, 512, 512,
                                            b1, ffbuf, nullptr, nullptr, nullptr);
  // FF2a: ffbuf x w2[:, 0:1024] -> vbuf (bf16 partial, no bias)
  gemm8<4><<<dim3(2,181), 512, 0, stream>>>(ffbuf, w2_b, 1024, 512, 1024, 2048,
                                            b2, vbuf, nullptr, nullptr, nullptr);
  // FF1b: h x w1[1024:2048,:] + relu -> ffbuf
  gemm8<2><<<dim3(4,181), 512, 0, stream>>>(kbuf, w1_b + (size_t)1024*512, 512, 1024, 512, 512,
                                            b1 + 1024, ffbuf, nullptr, nullptr, nullptr);
  // FF2b: ffbuf x w2[:, 1024:2048] + b2 + h + partial -> vbuf (in place)
  gemm8<5><<<dim3(2,181), 512, 0, stream>>>(ffbuf, w2_b + 1024, 1024, 512, 1024, 2048,
                                            b2, vbuf, nullptr, kbuf, vbuf);
  // LN2 -> d_out (fp32)
  ln_kernel<1><<<11584, 256, 0, stream>>>(vbuf, g2, be2, d_out);
}

// Round 7
// 574.987 us; speedup vs baseline: 1.0421x; 1.0421x over previous
//
#include <hip/hip_runtime.h>
#include <math.h>

typedef unsigned short u16;
typedef unsigned int u32;
typedef short bf16x8 __attribute__((ext_vector_type(8)));
typedef unsigned short u16x8 __attribute__((ext_vector_type(8)));
typedef float f32x4 __attribute__((ext_vector_type(4)));

#define DEV static __device__ __forceinline__

#define BB 256
#define NN 181
#define DD 512
#define HH 8
#define DKk 64
#define NPAD 192
#define MTOT (BB*NN)          // 46336
#define QKV_ELEMS (23724032u) // B*H*N*64
#define WS_NEEDED 196384768ull

DEV u16 f2bf(float f){
  u32 u = __float_as_uint(f);
  u32 r = (u + 0x7FFFu + ((u >> 16) & 1u)) >> 16;
  return (u16)r;
}
DEV float bf2f(u16 h){ return __uint_as_float(((u32)h) << 16); }
DEV bf16x8 as_bf(u16x8 v){ return __builtin_bit_cast(bf16x8, v); }

DEV void gl_lds16(const u16* g, u16* l){
  __builtin_amdgcn_global_load_lds(
      (const __attribute__((address_space(1))) unsigned int*)g,
      (__attribute__((address_space(3))) unsigned int*)l, 16, 0, 0);
}

// ---------------- unified prep: casts + bias table + bias concat ----------------
DEV void cast8(const float* __restrict__ src, u16* __restrict__ dst, int u){
  const float4* p = reinterpret_cast<const float4*>(src + (size_t)u*8);
  float4 a = p[0], b = p[1];
  u16x8 o;
  o[0]=f2bf(a.x); o[1]=f2bf(a.y); o[2]=f2bf(a.z); o[3]=f2bf(a.w);
  o[4]=f2bf(b.x); o[5]=f2bf(b.y); o[6]=f2bf(b.z); o[7]=f2bf(b.w);
  *reinterpret_cast<u16x8*>(dst + (size_t)u*8) = o;
}

#define SEG_X  2965504
#define SEG_Q  2998272
#define SEG_K  3031040
#define SEG_V  3063808
#define SEG_O  3096576
#define SEG_W1 3227648
#define SEG_W2 3358720
#define SEG_BI 3367936
#define SEG_BC 3368128

__global__ __launch_bounds__(256) void prep_kernel(
    const float* __restrict__ x,  const float* __restrict__ Wq,
    const float* __restrict__ Wk, const float* __restrict__ Wv,
    const float* __restrict__ Wo, const float* __restrict__ w1,
    const float* __restrict__ w2, const float* __restrict__ bq,
    const float* __restrict__ bk, const float* __restrict__ bv,
    const int* __restrict__ mask,
    u16* __restrict__ xb, u16* __restrict__ wqkv, u16* __restrict__ wo_b,
    u16* __restrict__ w1_b, u16* __restrict__ w2_b,
    float* __restrict__ biasA, float* __restrict__ bqkv)
{
  int u = blockIdx.x*256 + threadIdx.x;
  if (u < SEG_X)  { cast8(x,  xb,            u);          return; }
  if (u < SEG_Q)  { cast8(Wq, wqkv,          u - SEG_X);  return; }
  if (u < SEG_K)  { cast8(Wk, wqkv + 262144, u - SEG_Q);  return; }
  if (u < SEG_V)  { cast8(Wv, wqkv + 524288, u - SEG_K);  return; }
  if (u < SEG_O)  { cast8(Wo, wo_b,          u - SEG_V);  return; }
  if (u < SEG_W1) { cast8(w1, w1_b,          u - SEG_O);  return; }
  if (u < SEG_W2) { cast8(w2, w2_b,          u - SEG_W1); return; }
  if (u < SEG_BI) {
    int base = (u - SEG_W2)*8;
    #pragma unroll
    for (int j=0;j<8;++j){
      int idx = base + j;
      int g = idx / (NPAD*NPAD);
      int rem = idx % (NPAD*NPAD);
      int q = rem / NPAD, k = rem % NPAD;
      float v;
      if (k >= NN) v = -INFINITY;
      else if (q >= NN) v = 0.f;
      else {
        bool qv = q < 121, kv = k < 121;
        bool allowed = (g == 0) ? (qv != kv) : (qv == kv);
        if (!allowed) v = -INFINITY;
        else {
          int mb = (g == 0 && !qv) ? mask[k*NN + q] : mask[q*NN + k];
          v = mb ? -1e9f : 0.f;
        }
      }
      biasA[idx] = v;
    }
    return;
  }
  if (u < SEG_BC) {
    int base = (u - SEG_BI)*8;
    #pragma unroll
    for (int j=0;j<8;++j){
      int e = base + j;
      bqkv[e] = (e < 512) ? bq[e] : (e < 1024) ? bk[e-512] : bv[e-1024];
    }
    return;
  }
}

// ================= 256x256 register-resident GEMM, C = A(MxK) * B(NxK)^T =======
// 512 thr = 8 waves (2M x 4N), per-wave output 128x64. Per K-tile (BK=64):
// two k-slices; per slice each wave loads af[8]+bg[4] (12 ds_read_b128) and
// runs a 32-MFMA cluster -> 24 reads / 64 MFMA per wave per K-tile (vs 48 in
// the r6 phase schedule). Staging/swizzle/remap identical to r6 (verified).
// LDS 128KB dbuf, 1 block/CU, counted vmcnt(8) (8 gl_lds per tile-stage).
// EPI 0: QKV scatter (+0.125 Q); 1: +bias+resf(f32); 2: +bias+relu;
// EPI 4: raw->bf16 (partial);    5: +bias+bf2f(resb)+bf2f(res2)
#define STAGE4(SB, KT) do { \
    int kt_ = (KT); if (kt_ >= ntiles) kt_ = 0; \
    const size_t ko_ = (size_t)kt_*64; \
    gl_lds16(stA + ko_,                   &ldsT[SB][0][0][wave*512]); \
    gl_lds16(stA + (size_t)64*lda  + ko_, &ldsT[SB][0][0][wave*512 + 4096]); \
    gl_lds16(stA + (size_t)128*lda + ko_, &ldsT[SB][0][1][wave*512]); \
    gl_lds16(stA + (size_t)192*lda + ko_, &ldsT[SB][0][1][wave*512 + 4096]); \
    gl_lds16(stB + ko_,                   &ldsT[SB][1][0][wave*512]); \
    gl_lds16(stB + (size_t)64*ldb  + ko_, &ldsT[SB][1][0][wave*512 + 4096]); \
    gl_lds16(stB + (size_t)128*ldb + ko_, &ldsT[SB][1][1][wave*512]); \
    gl_lds16(stB + (size_t)192*ldb + ko_, &ldsT[SB][1][1][wave*512 + 4096]); \
  } while(0)

#define RD(KH) do { \
    _Pragma("unroll") for (int f_=0; f_<8; ++f_) \
      af_[f_] = *reinterpret_cast<const bf16x8*>( \
          aB + (f_>>2)*8192 + (f_&3)*2048 + (KH)*512 + rdoffA); \
    _Pragma("unroll") for (int n_=0; n_<4; ++n_) \
      bg_[n_] = *reinterpret_cast<const bf16x8*>( \
          bB + (n_>>1)*8192 + (n_&1)*4096 + (KH)*512 + rdoffB); \
  } while(0)

#define MFMA32 do { \
    _Pragma("unroll") for (int f_=0; f_<8; ++f_) \
      _Pragma("unroll") for (int n_=0; n_<4; ++n_) \
        acc[f_][n_] = __builtin_amdgcn_mfma_f32_16x16x32_bf16( \
            af_[f_], bg_[n_], acc[f_][n_], 0,0,0); \
  } while(0)

#define SGB __builtin_amdgcn_sched_barrier(0)

template<int EPI>
__global__ __launch_bounds__(512, 2) void gemmR(
    const u16* __restrict__ A, const u16* __restrict__ Bw,
    int K, int N, int lda, int ldb,
    const float* __restrict__ bias,
    u16* __restrict__ outb,
    const float* __restrict__ resf,
    const u16* __restrict__ resb,
    const u16* __restrict__ res2)
{
  __shared__ u16 ldsT[2][2][2][8192];   // [buf][A/B][half][128x64] 128 KiB
  const int tid = threadIdx.x, lane = tid & 63, wave = tid >> 6;
  const int lo = lane & 15, hi = lane >> 4;
  const int wm = wave >> 2, wn = wave & 3;

  // m204 bijective XCD remap, nt-fastest ids
  const int nwg = gridDim.x * gridDim.y;
  const int bid = blockIdx.x + gridDim.x * blockIdx.y;
  const int q8 = nwg >> 3, r8 = nwg & 7;
  const int xcd = bid & 7, j8 = bid >> 3;
  const int wgid = (xcd < r8 ? xcd*(q8+1) : r8*(q8+1) + (xcd-r8)*q8) + j8;
  const int ntb = wgid % gridDim.x, mt = wgid / gridDim.x;
  const int ntiles = K >> 6;

  // staging source (inverse subtile swizzle; dest linear per-wave slot) — r6-verified
  const int pr = ((tid >> 7) << 4) | ((tid >> 2) & 15);
  const int pc = (((tid >> 6) & 1) << 5) | (((tid & 3) * 8) ^ (((tid >> 5) & 1) << 4));
  const u16* stA = A  + (size_t)(mt*256 + pr) * lda + pc;
  const u16* stB = Bw + (size_t)(ntb*256 + pr) * ldb + pc;
  // swizzled fragment-read bases (elements) — r6-verified
  const int swz = (hi*8) ^ ((lo & 8) << 1);
  const int rdoffA = wm*1024 + lo*32 + swz;
  const int rdoffB = wn*1024 + lo*32 + swz;

  f32x4 acc[8][4];
  #pragma unroll
  for (int f=0; f<8; ++f)
    #pragma unroll
    for (int n=0; n<4; ++n) acc[f][n] = f32x4{0.f,0.f,0.f,0.f};

  // prologue: stage tile0 -> buf0, tile1 -> buf1 (16 loads); wait tile0 (8 left)
  STAGE4(0, 0);
  STAGE4(1, 1);
  asm volatile("s_waitcnt vmcnt(8)" ::: "memory");
  SGB;
  __builtin_amdgcn_s_barrier();
  SGB;

  for (int kt = 0; kt < ntiles; ++kt){
    const int cbuf = kt & 1;
    const u16* aB = &ldsT[cbuf][0][0][0];
    const u16* bB = &ldsT[cbuf][1][0][0];
    bf16x8 af_[8], bg_[4];
    // k-slice 0: load frags, MFMA cluster
    RD(0);
    asm volatile("s_waitcnt lgkmcnt(0)" ::: "memory");
    SGB;
    __builtin_amdgcn_s_setprio(1);
    MFMA32;
    __builtin_amdgcn_s_setprio(0);
    SGB;
    // k-slice 1: load frags (reads of cbuf complete before barrier)
    RD(1);
    asm volatile("s_waitcnt lgkmcnt(0)" ::: "memory");
    SGB;
    __builtin_amdgcn_s_barrier();        // all waves done reading buf cbuf
    SGB;
    STAGE4(cbuf, kt + 2);                // refill cbuf with tile kt+2
    SGB;
    __builtin_amdgcn_s_setprio(1);
    MFMA32;                              // hides staging issue + latency
    __builtin_amdgcn_s_setprio(0);
    SGB;
    asm volatile("s_waitcnt vmcnt(8)" ::: "memory");  // tile kt+1 landed (mine)
    SGB;
    __builtin_amdgcn_s_barrier();        // tile kt+1 landed (all waves)
    SGB;
  }
  asm volatile("s_waitcnt vmcnt(0)" ::: "memory");

  // epilogue: row = mt*256 + wm*16 + f*32 + hi*4 + rg; col = ntb*256 + wn*16 + n*64 + lo
  float bv[4];
  #pragma unroll
  for (int n=0; n<4; ++n) bv[n] = bias[ntb*256 + wn*16 + n*64 + lo];
  #pragma unroll
  for (int f=0; f<8; ++f){
    #pragma unroll
    for (int rg=0; rg<4; ++rg){
      const int row = mt*256 + wm*16 + f*32 + hi*4 + rg;
      if constexpr (EPI == 0){
        const int bi = row / NN, ni = row - bi*NN;
        #pragma unroll
        for (int n=0; n<4; ++n){
          const int gcol = ntb*256 + wn*16 + n*64 + lo;
          float v = acc[f][n][rg] + bv[n];
          int which = gcol >> 9;
          int hh = (gcol >> 6) & 7;
          int d  = gcol & 63;
          if (which == 0) v *= 0.125f;
          outb[(size_t)which*QKV_ELEMS + (((size_t)bi*HH + hh)*NN + ni)*DKk + d] = f2bf(v);
        }
      } else {
        #pragma unroll
        for (int n=0; n<4; ++n){
          const int gcol = ntb*256 + wn*16 + n*64 + lo;
          float v = acc[f][n][rg];
          if constexpr (EPI == 1){
            v += bv[n] + resf[(size_t)row*N + gcol];
          } else if constexpr (EPI == 2){
            v = fmaxf(v + bv[n], 0.f);
          } else if constexpr (EPI == 5){
            v += bv[n] + bf2f(resb[(size_t)row*N + gcol]) + bf2f(res2[(size_t)row*N + gcol]);
          }
          outb[(size_t)row*N + gcol] = f2bf(v);
        }
      }
    }
  }
}

// ---------------- fused segment attention (unchanged, verified r2-r6) ----------------
__global__ __launch_bounds__(256) void attn_kernel(
    const u16* __restrict__ Qg, const u16* __restrict__ Kg, const u16* __restrict__ Vg,
    const float* __restrict__ biasA, u16* __restrict__ ctx)
{
  __shared__ u16 Kb[NPAD*72];
  __shared__ u16 Vt[64*200];
  __shared__ u16 Pl[4*16*200];
  const int tid = threadIdx.x, lane = tid & 63, wave = tid >> 6;
  const int lo = lane & 15, hi = lane >> 4;
  const int bh = blockIdx.x;
  const int h = bh & 7, g = h >> 2, b = bh >> 3;
  const size_t base = (size_t)bh * NN * DKk;

  #pragma unroll
  for (int it=0; it<6; ++it){
    int row = it*32 + (tid >> 3);
    int cb = (tid & 7)*8;
    u16x8 val = {0,0,0,0,0,0,0,0};
    if (row < NN) val = *reinterpret_cast<const u16x8*>(Kg + base + (size_t)row*DKk + cb);
    *reinterpret_cast<u16x8*>(&Kb[row*72 + cb]) = val;
  }
  #pragma unroll
  for (int it=0; it<6; ++it){
    int row = it*32 + (tid >> 3);
    int cb = (tid & 7)*8;
    u16x8 val = {0,0,0,0,0,0,0,0};
    if (row < NN) val = *reinterpret_cast<const u16x8*>(Vg + base + (size_t)row*DKk + cb);
    *reinterpret_cast<u16x8*>(&Pl[row*64 + cb]) = val;
  }
  __syncthreads();
  #pragma unroll
  for (int j=0;j<6;++j){
    int task = j*256 + tid;
    int d = task & 63;
    int nc = task >> 6;
    u16x8 tv;
    #pragma unroll
    for (int i=0;i<8;++i) tv[i] = Pl[(nc*8+i)*64 + d];
    *reinterpret_cast<u16x8*>(&Vt[d*200 + nc*8]) = tv;
  }
  __syncthreads();

  u16* pw = Pl + wave*16*200;

  for (int rb = wave; rb < 12; rb += 4){
    const int q0 = rb*16;
    const int qrow = q0 + lo;
    bf16x8 qa[2];
    #pragma unroll
    for (int kk=0;kk<2;++kk){
      u16x8 val = {0,0,0,0,0,0,0,0};
      if (qrow < NN) val = *reinterpret_cast<const u16x8*>(Qg + base + (size_t)qrow*DKk + kk*32 + hi*8);
      qa[kk] = as_bf(val);
    }
    f32x4 s[12];
    #pragma unroll
    for (int c=0;c<12;++c){
      f32x4 a = f32x4{0.f,0.f,0.f,0.f};
      #pragma unroll
      for (int kk=0;kk<2;++kk){
        bf16x8 kb = *reinterpret_cast<const bf16x8*>(&Kb[(c*16+lo)*72 + kk*32 + hi*8]);
        a = __builtin_amdgcn_mfma_f32_16x16x32_bf16(qa[kk], kb, a, 0,0,0);
      }
      s[c] = a;
    }
    const float* brow = biasA + ((size_t)g*NPAD + q0 + hi*4)*NPAD + lo;
    #pragma unroll
    for (int r=0;r<4;++r)
      #pragma unroll
      for (int c=0;c<12;++c)
        s[c][r] += brow[r*NPAD + c*16];
    float inv[4];
    #pragma unroll
    for (int r=0;r<4;++r){
      float m = s[0][r];
      #pragma unroll
      for (int c=1;c<12;++c) m = fmaxf(m, s[c][r]);
      #pragma unroll
      for (int off=1; off<16; off<<=1) m = fmaxf(m, __shfl_xor(m, off, 64));
      float t = 0.f;
      #pragma unroll
      for (int c=0;c<12;++c){ float e = __expf(s[c][r] - m); s[c][r] = e; t += e; }
      #pragma unroll
      for (int off=1; off<16; off<<=1) t += __shfl_xor(t, off, 64);
      inv[r] = 1.0f / t;
    }
    #pragma unroll
    for (int c=0;c<12;++c)
      #pragma unroll
      for (int r=0;r<4;++r)
        pw[(hi*4+r)*200 + c*16 + lo] = f2bf(s[c][r] * inv[r]);
    asm volatile("s_waitcnt lgkmcnt(0)" ::: "memory");
    __builtin_amdgcn_sched_barrier(0);
    bf16x8 pa[6];
    #pragma unroll
    for (int c6=0;c6<6;++c6)
      pa[c6] = *reinterpret_cast<const bf16x8*>(&pw[lo*200 + c6*32 + hi*8]);
    #pragma unroll
    for (int dt=0;dt<4;++dt){
      f32x4 a = f32x4{0.f,0.f,0.f,0.f};
      #pragma unroll
      for (int c6=0;c6<6;++c6){
        bf16x8 vb = *reinterpret_cast<const bf16x8*>(&Vt[(dt*16+lo)*200 + c6*32 + hi*8]);
        a = __builtin_amdgcn_mfma_f32_16x16x32_bf16(pa[c6], vb, a, 0,0,0);
      }
      #pragma unroll
      for (int r=0;r<4;++r){
        int q = q0 + hi*4 + r;
        if (q < NN)
          ctx[((size_t)b*NN + q)*DD + h*DKk + dt*16 + lo] = f2bf(a[r]);
      }
    }
  }
}

// ---------------- LayerNorm over D=512, one wave per row ----------------
template<int OUTF32>
__global__ __launch_bounds__(256) void ln_kernel(
    const u16* __restrict__ in, const float* __restrict__ gamma,
    const float* __restrict__ beta, void* __restrict__ outp)
{
  const int row = blockIdx.x*4 + (threadIdx.x >> 6);
  const int lane = threadIdx.x & 63;
  u16x8 rv = *reinterpret_cast<const u16x8*>(in + (size_t)row*512 + lane*8);
  float x[8]; float s = 0.f, s2 = 0.f;
  #pragma unroll
  for (int i=0;i<8;++i){ x[i] = bf2f(rv[i]); s += x[i]; s2 += x[i]*x[i]; }
  #pragma unroll
  for (int off=32; off>=1; off>>=1){ s += __shfl_xor(s, off, 64); s2 += __shfl_xor(s2, off, 64); }
  const float mu = s * (1.f/512.f);
  const float var = s2 * (1.f/512.f) - mu*mu;
  const float rstd = rsqrtf(var + 1e-5f);
  float4 ga = *reinterpret_cast<const float4*>(gamma + lane*8);
  float4 gb = *reinterpret_cast<const float4*>(gamma + lane*8 + 4);
  float4 ba = *reinterpret_cast<const float4*>(beta + lane*8);
  float4 bb = *reinterpret_cast<const float4*>(beta + lane*8 + 4);
  float gg[8] = {ga.x,ga.y,ga.z,ga.w,gb.x,gb.y,gb.z,gb.w};
  float bt[8] = {ba.x,ba.y,ba.z,ba.w,bb.x,bb.y,bb.z,bb.w};
  if constexpr (OUTF32){
    float o[8];
    #pragma unroll
    for (int i=0;i<8;++i) o[i] = (x[i]-mu)*rstd*gg[i] + bt[i];
    float4* op = reinterpret_cast<float4*>((float*)outp + (size_t)row*512 + lane*8);
    op[0] = make_float4(o[0],o[1],o[2],o[3]);
    op[1] = make_float4(o[4],o[5],o[6],o[7]);
  } else {
    u16x8 o;
    #pragma unroll
    for (int i=0;i<8;++i) o[i] = f2bf((x[i]-mu)*rstd*gg[i] + bt[i]);
    *reinterpret_cast<u16x8*>((u16*)outp + (size_t)row*512 + lane*8) = o;
  }
}

// ---------------- launch ----------------
// ws map (total 196,384,768 B) — identical to r4-r6:
//   [0        ..  2097152) w1_b     [2097152 ..  4194304) w2_b
//   [4194304  ..  5767168) wqkv     [5767168 ..  6291456) wo_b
//   [6291456  ..  6586368) biasA    [6586368 ..  6592512) bqkv
//   [6592512  .. 54040576) xb  : x bf16 -> ctx
//   [54040576 ..101488640) qbuf: Q -> r1
//   [101488640..148936704) kbuf: K -> h
//   [148936704..196384768) vbuf: V -> FF2a partial -> s2
//   ffbuf = ws+4194304 (46336x1024 bf16 ends 99,090,432 < kbuf)
extern "C" void kernel_launch(void* const* d_in, const int* in_sizes, int n_in,
                              void* d_out, int out_size, void* d_ws, size_t ws_size,
                              hipStream_t stream)
{
  if (ws_size < WS_NEEDED) return;

  const float* x   = (const float*)d_in[0];
  const int*   mask= (const int*)  d_in[1];
  const float* Wq  = (const float*)d_in[2];
  const float* bq  = (const float*)d_in[3];
  const float* Wk  = (const float*)d_in[4];
  const float* bk  = (const float*)d_in[5];
  const float* Wv  = (const float*)d_in[6];
  const float* bv  = (const float*)d_in[7];
  const float* Wo  = (const float*)d_in[8];
  const float* bo  = (const float*)d_in[9];
  const float* w1  = (const float*)d_in[10];
  const float* b1  = (const float*)d_in[11];
  const float* w2  = (const float*)d_in[12];
  const float* b2  = (const float*)d_in[13];
  const float* g1  = (const float*)d_in[14];
  const float* be1 = (const float*)d_in[15];
  const float* g2  = (const float*)d_in[16];
  const float* be2 = (const float*)d_in[17];

  char* ws = (char*)d_ws;
  u16*   w1_b  = (u16*)  (ws + 0);
  u16*   w2_b  = (u16*)  (ws + 2097152);
  u16*   wqkv  = (u16*)  (ws + 4194304);
  u16*   wo_b  = (u16*)  (ws + 5767168);
  float* biasA = (float*)(ws + 6291456);
  float* bqkv  = (float*)(ws + 6586368);
  u16*   xb    = (u16*)  (ws + 6592512);
  u16*   qbuf  = (u16*)  (ws + 54040576);
  u16*   kbuf  = qbuf + QKV_ELEMS;
  u16*   vbuf  = qbuf + 2*QKV_ELEMS;
  u16*   ffbuf = (u16*)  (ws + 4194304);

  // one fused prep launch
  prep_kernel<<<13157, 256, 0, stream>>>(x, Wq, Wk, Wv, Wo, w1, w2, bq, bk, bv,
                                         mask, xb, wqkv, wo_b, w1_b, w2_b, biasA, bqkv);

  // QKV projection (scatter to [B,H,N,64] bf16, Q scaled by 1/8)
  gemmR<0><<<dim3(6,181), 512, 0, stream>>>(xb, wqkv, 512, 1536, 512, 512,
                                            bqkv, qbuf, nullptr, nullptr, nullptr);
  // fused segment attention -> ctx (xb region)
  attn_kernel<<<2048, 256, 0, stream>>>(qbuf, kbuf, vbuf, biasA, xb);
  // Wo projection + bo + x residual -> r1 (qbuf)
  gemmR<1><<<dim3(2,181), 512, 0, stream>>>(xb, wo_b, 512, 512, 512, 512,
                                            bo, qbuf, x, nullptr, nullptr);
  // LN1 -> h (kbuf)
  ln_kernel<0><<<11584, 256, 0, stream>>>(qbuf, g1, be1, kbuf);
  // FF1a: h x w1[0:1024,:] + relu -> ffbuf
  gemmR<2><<<dim3(4,181), 512, 0, stream>>>(kbuf, w1_b, 512, 1024, 512, 512,
                                            b1, ffbuf, nullptr, nullptr, nullptr);
  // FF2a: ffbuf x w2[:, 0:1024] -> vbuf (bf16 partial, no bias)
  gemmR<4><<<dim3(2,181), 512, 0, stream>>>(ffbuf, w2_b, 1024, 512, 1024, 2048,
                                            b2, vbuf, nullptr, nullptr, nullptr);
  // FF1b: h x w1[1024:2048,:] + relu -> ffbuf
  gemmR<2><<<dim3(4,181), 512, 0, stream>>>(kbuf, w1_b + (size_t)1024*512, 512, 1024, 512, 512,
                                            b1 + 1024, ffbuf, nullptr, nullptr, nullptr);
  // FF2b: ffbuf x w2[:, 1024:2048] + b2 + h + partial -> vbuf (in place)
  gemmR<5><<<dim3(2,181), 512, 0, stream>>>(ffbuf, w2_b + 1024, 1024, 512, 1024, 2048,
                                            b2, vbuf, nullptr, kbuf, vbuf);
  // LN2 -> d_out (fp32)
  ln_kernel<1><<<11584, 256, 0, stream>>>(vbuf, g2, be2, d_out);
}

// Round 8
// 536.130 us; speedup vs baseline: 1.1177x; 1.0725x over previous
//
#include <hip/hip_runtime.h>
#include <math.h>

typedef unsigned short u16;
typedef unsigned int u32;
typedef short bf16x8 __attribute__((ext_vector_type(8)));
typedef unsigned short u16x8 __attribute__((ext_vector_type(8)));
typedef float f32x4 __attribute__((ext_vector_type(4)));

#define DEV static __device__ __forceinline__

#define BB 256
#define NN 181
#define DD 512
#define HH 8
#define DKk 64
#define NPAD 192
#define MTOT (BB*NN)          // 46336
#define QKV_ELEMS (23724032u) // B*H*N*64
#define WS_NEEDED 196384768ull
#define LSTR 264              // bounce-tile row stride (u16): 528B = 33*16 aligned

DEV u16 f2bf(float f){
  u32 u = __float_as_uint(f);
  u32 r = (u + 0x7FFFu + ((u >> 16) & 1u)) >> 16;
  return (u16)r;
}
DEV float bf2f(u16 h){ return __uint_as_float(((u32)h) << 16); }
DEV bf16x8 as_bf(u16x8 v){ return __builtin_bit_cast(bf16x8, v); }

DEV void gl_lds16(const u16* g, u16* l){
  __builtin_amdgcn_global_load_lds(
      (const __attribute__((address_space(1))) unsigned int*)g,
      (__attribute__((address_space(3))) unsigned int*)l, 16, 0, 0);
}

// ---------------- unified prep: casts + bias table + bias concat ----------------
DEV void cast8(const float* __restrict__ src, u16* __restrict__ dst, int u){
  const float4* p = reinterpret_cast<const float4*>(src + (size_t)u*8);
  float4 a = p[0], b = p[1];
  u16x8 o;
  o[0]=f2bf(a.x); o[1]=f2bf(a.y); o[2]=f2bf(a.z); o[3]=f2bf(a.w);
  o[4]=f2bf(b.x); o[5]=f2bf(b.y); o[6]=f2bf(b.z); o[7]=f2bf(b.w);
  *reinterpret_cast<u16x8*>(dst + (size_t)u*8) = o;
}

#define SEG_X  2965504
#define SEG_Q  2998272
#define SEG_K  3031040
#define SEG_V  3063808
#define SEG_O  3096576
#define SEG_W1 3227648
#define SEG_W2 3358720
#define SEG_BI 3367936
#define SEG_BC 3368128

__global__ __launch_bounds__(256) void prep_kernel(
    const float* __restrict__ x,  const float* __restrict__ Wq,
    const float* __restrict__ Wk, const float* __restrict__ Wv,
    const float* __restrict__ Wo, const float* __restrict__ w1,
    const float* __restrict__ w2, const float* __restrict__ bq,
    const float* __restrict__ bk, const float* __restrict__ bv,
    const int* __restrict__ mask,
    u16* __restrict__ xb, u16* __restrict__ wqkv, u16* __restrict__ wo_b,
    u16* __restrict__ w1_b, u16* __restrict__ w2_b,
    float* __restrict__ biasA, float* __restrict__ bqkv)
{
  int u = blockIdx.x*256 + threadIdx.x;
  if (u < SEG_X)  { cast8(x,  xb,            u);          return; }
  if (u < SEG_Q)  { cast8(Wq, wqkv,          u - SEG_X);  return; }
  if (u < SEG_K)  { cast8(Wk, wqkv + 262144, u - SEG_Q);  return; }
  if (u < SEG_V)  { cast8(Wv, wqkv + 524288, u - SEG_K);  return; }
  if (u < SEG_O)  { cast8(Wo, wo_b,          u - SEG_V);  return; }
  if (u < SEG_W1) { cast8(w1, w1_b,          u - SEG_O);  return; }
  if (u < SEG_W2) { cast8(w2, w2_b,          u - SEG_W1); return; }
  if (u < SEG_BI) {
    int base = (u - SEG_W2)*8;
    #pragma unroll
    for (int j=0;j<8;++j){
      int idx = base + j;
      int g = idx / (NPAD*NPAD);
      int rem = idx % (NPAD*NPAD);
      int q = rem / NPAD, k = rem % NPAD;
      float v;
      if (k >= NN) v = -INFINITY;
      else if (q >= NN) v = 0.f;
      else {
        bool qv = q < 121, kv = k < 121;
        bool allowed = (g == 0) ? (qv != kv) : (qv == kv);
        if (!allowed) v = -INFINITY;
        else {
          int mb = (g == 0 && !qv) ? mask[k*NN + q] : mask[q*NN + k];
          v = mb ? -1e9f : 0.f;
        }
      }
      biasA[idx] = v;
    }
    return;
  }
  if (u < SEG_BC) {
    int base = (u - SEG_BI)*8;
    #pragma unroll
    for (int j=0;j<8;++j){
      int e = base + j;
      bqkv[e] = (e < 512) ? bq[e] : (e < 1024) ? bk[e-512] : bv[e-1024];
    }
    return;
  }
}

// ================= 256x256 register-resident GEMM, C = A(MxK) * B(NxK)^T =======
// K-loop identical to r7 (verified). New: LDS-bounce epilogue -> 16B/lane
// coalesced stores. EPI 0: QKV scatter (+0.125 Q); 1: +bias+resf(f32);
// 2: +bias+relu; 5: +bias+bf2f(resb).
#define STAGE4(SB, KT) do { \
    int kt_ = (KT); if (kt_ >= ntiles) kt_ = 0; \
    const size_t ko_ = (size_t)kt_*64; \
    gl_lds16(stA + ko_,                   &ldsT[SB][0][0][wave*512]); \
    gl_lds16(stA + (size_t)64*lda  + ko_, &ldsT[SB][0][0][wave*512 + 4096]); \
    gl_lds16(stA + (size_t)128*lda + ko_, &ldsT[SB][0][1][wave*512]); \
    gl_lds16(stA + (size_t)192*lda + ko_, &ldsT[SB][0][1][wave*512 + 4096]); \
    gl_lds16(stB + ko_,                   &ldsT[SB][1][0][wave*512]); \
    gl_lds16(stB + (size_t)64*ldb  + ko_, &ldsT[SB][1][0][wave*512 + 4096]); \
    gl_lds16(stB + (size_t)128*ldb + ko_, &ldsT[SB][1][1][wave*512]); \
    gl_lds16(stB + (size_t)192*ldb + ko_, &ldsT[SB][1][1][wave*512 + 4096]); \
  } while(0)

#define RD(KH) do { \
    _Pragma("unroll") for (int f_=0; f_<8; ++f_) \
      af_[f_] = *reinterpret_cast<const bf16x8*>( \
          aB + (f_>>2)*8192 + (f_&3)*2048 + (KH)*512 + rdoffA); \
    _Pragma("unroll") for (int n_=0; n_<4; ++n_) \
      bg_[n_] = *reinterpret_cast<const bf16x8*>( \
          bB + (n_>>1)*8192 + (n_&1)*4096 + (KH)*512 + rdoffB); \
  } while(0)

#define MFMA32 do { \
    _Pragma("unroll") for (int f_=0; f_<8; ++f_) \
      _Pragma("unroll") for (int n_=0; n_<4; ++n_) \
        acc[f_][n_] = __builtin_amdgcn_mfma_f32_16x16x32_bf16( \
            af_[f_], bg_[n_], acc[f_][n_], 0,0,0); \
  } while(0)

#define SGB __builtin_amdgcn_sched_barrier(0)

template<int EPI>
__global__ __launch_bounds__(512, 2) void gemmR(
    const u16* __restrict__ A, const u16* __restrict__ Bw,
    int K, int N, int lda, int ldb,
    const float* __restrict__ bias,
    u16* __restrict__ outb,
    const float* __restrict__ resf,
    const u16* __restrict__ resb)
{
  __shared__ u16 ldsAll[67584];         // 135,168 B: staging (128K) / bounce tile
  u16 (*ldsT)[2][2][8192] = reinterpret_cast<u16(*)[2][2][8192]>(ldsAll);
  const int tid = threadIdx.x, lane = tid & 63, wave = tid >> 6;
  const int lo = lane & 15, hi = lane >> 4;
  const int wm = wave >> 2, wn = wave & 3;

  // m204 bijective XCD remap, nt-fastest ids
  const int nwg = gridDim.x * gridDim.y;
  const int bid = blockIdx.x + gridDim.x * blockIdx.y;
  const int q8 = nwg >> 3, r8 = nwg & 7;
  const int xcd = bid & 7, j8 = bid >> 3;
  const int wgid = (xcd < r8 ? xcd*(q8+1) : r8*(q8+1) + (xcd-r8)*q8) + j8;
  const int ntb = wgid % gridDim.x, mt = wgid / gridDim.x;
  const int ntiles = K >> 6;

  // staging source (inverse subtile swizzle; dest linear per-wave slot) — verified
  const int pr = ((tid >> 7) << 4) | ((tid >> 2) & 15);
  const int pc = (((tid >> 6) & 1) << 5) | (((tid & 3) * 8) ^ (((tid >> 5) & 1) << 4));
  const u16* stA = A  + (size_t)(mt*256 + pr) * lda + pc;
  const u16* stB = Bw + (size_t)(ntb*256 + pr) * ldb + pc;
  // swizzled fragment-read bases (elements) — verified
  const int swz = (hi*8) ^ ((lo & 8) << 1);
  const int rdoffA = wm*1024 + lo*32 + swz;
  const int rdoffB = wn*1024 + lo*32 + swz;

  f32x4 acc[8][4];
  #pragma unroll
  for (int f=0; f<8; ++f)
    #pragma unroll
    for (int n=0; n<4; ++n) acc[f][n] = f32x4{0.f,0.f,0.f,0.f};

  // prologue: stage tile0 -> buf0, tile1 -> buf1 (16 loads); wait tile0 (8 left)
  STAGE4(0, 0);
  STAGE4(1, 1);
  asm volatile("s_waitcnt vmcnt(8)" ::: "memory");
  SGB;
  __builtin_amdgcn_s_barrier();
  SGB;

  for (int kt = 0; kt < ntiles; ++kt){
    const int cbuf = kt & 1;
    const u16* aB = &ldsT[cbuf][0][0][0];
    const u16* bB = &ldsT[cbuf][1][0][0];
    bf16x8 af_[8], bg_[4];
    RD(0);
    asm volatile("s_waitcnt lgkmcnt(0)" ::: "memory");
    SGB;
    __builtin_amdgcn_s_setprio(1);
    MFMA32;
    __builtin_amdgcn_s_setprio(0);
    SGB;
    RD(1);
    asm volatile("s_waitcnt lgkmcnt(0)" ::: "memory");
    SGB;
    __builtin_amdgcn_s_barrier();        // all waves done reading buf cbuf
    SGB;
    STAGE4(cbuf, kt + 2);                // refill cbuf with tile kt+2
    SGB;
    __builtin_amdgcn_s_setprio(1);
    MFMA32;
    __builtin_amdgcn_s_setprio(0);
    SGB;
    asm volatile("s_waitcnt vmcnt(8)" ::: "memory");  // tile kt+1 landed (mine)
    SGB;
    __builtin_amdgcn_s_barrier();        // tile kt+1 landed (all waves)
    SGB;
  }

  // ---------------- LDS-bounce epilogue ----------------
  asm volatile("s_waitcnt vmcnt(0)" ::: "memory");  // drain staging queue
  SGB;
  __builtin_amdgcn_s_barrier();                     // all waves drained
  SGB;

  float bv[4];
  #pragma unroll
  for (int n=0; n<4; ++n) bv[n] = bias[ntb*256 + wn*16 + n*64 + lo];

  // write phase: final bf16 values into [256][LSTR] tile (conflict-free b16)
  #pragma unroll
  for (int f=0; f<8; ++f){
    #pragma unroll
    for (int rg=0; rg<4; ++rg){
      const int trow = wm*16 + f*32 + hi*4 + rg;
      const int grow = mt*256 + trow;
      #pragma unroll
      for (int n=0; n<4; ++n){
        const int tcol = wn*16 + n*64 + lo;
        float v = acc[f][n][rg] + bv[n];
        if constexpr (EPI == 0){
          if (((ntb*256 + tcol) >> 9) == 0) v *= 0.125f;   // Q scale
        } else if constexpr (EPI == 1){
          v += resf[(size_t)grow*N + ntb*256 + tcol];
        } else if constexpr (EPI == 2){
          v = fmaxf(v, 0.f);
        } else if constexpr (EPI == 5){
          v += bf2f(resb[(size_t)grow*N + ntb*256 + tcol]);
        }
        ldsAll[trow*LSTR + tcol] = f2bf(v);
      }
    }
  }
  __syncthreads();

  // readback: 16 passes x 16 rows; lane -> one 8-col chunk; 16B/lane stores
  const int rchunk = lane & 31;
  const int rrow0  = wave*2 + (lane >> 5);
  #pragma unroll
  for (int p=0; p<16; ++p){
    const int trow = rrow0 + p*16;
    const int grow = mt*256 + trow;
    u16x8 v = *reinterpret_cast<const u16x8*>(&ldsAll[trow*LSTR + rchunk*8]);
    if constexpr (EPI == 0){
      const int gcol = ntb*256 + rchunk*8;
      const int bi = grow / NN, ni = grow - bi*NN;
      const int which = gcol >> 9, hh = (gcol >> 6) & 7, d = gcol & 63;
      *reinterpret_cast<u16x8*>(outb + (size_t)which*QKV_ELEMS +
          (((size_t)bi*HH + hh)*NN + ni)*DKk + d) = v;
    } else {
      *reinterpret_cast<u16x8*>(outb + (size_t)grow*N + ntb*256 + rchunk*8) = v;
    }
  }
}

// ---------------- fused segment attention (unchanged, verified r2-r7) ----------------
__global__ __launch_bounds__(256) void attn_kernel(
    const u16* __restrict__ Qg, const u16* __restrict__ Kg, const u16* __restrict__ Vg,
    const float* __restrict__ biasA, u16* __restrict__ ctx)
{
  __shared__ u16 Kb[NPAD*72];
  __shared__ u16 Vt[64*200];
  __shared__ u16 Pl[4*16*200];
  const int tid = threadIdx.x, lane = tid & 63, wave = tid >> 6;
  const int lo = lane & 15, hi = lane >> 4;
  const int bh = blockIdx.x;
  const int h = bh & 7, g = h >> 2, b = bh >> 3;
  const size_t base = (size_t)bh * NN * DKk;

  #pragma unroll
  for (int it=0; it<6; ++it){
    int row = it*32 + (tid >> 3);
    int cb = (tid & 7)*8;
    u16x8 val = {0,0,0,0,0,0,0,0};
    if (row < NN) val = *reinterpret_cast<const u16x8*>(Kg + base + (size_t)row*DKk + cb);
    *reinterpret_cast<u16x8*>(&Kb[row*72 + cb]) = val;
  }
  #pragma unroll
  for (int it=0; it<6; ++it){
    int row = it*32 + (tid >> 3);
    int cb = (tid & 7)*8;
    u16x8 val = {0,0,0,0,0,0,0,0};
    if (row < NN) val = *reinterpret_cast<const u16x8*>(Vg + base + (size_t)row*DKk + cb);
    *reinterpret_cast<u16x8*>(&Pl[row*64 + cb]) = val;
  }
  __syncthreads();
  #pragma unroll
  for (int j=0;j<6;++j){
    int task = j*256 + tid;
    int d = task & 63;
    int nc = task >> 6;
    u16x8 tv;
    #pragma unroll
    for (int i=0;i<8;++i) tv[i] = Pl[(nc*8+i)*64 + d];
    *reinterpret_cast<u16x8*>(&Vt[d*200 + nc*8]) = tv;
  }
  __syncthreads();

  u16* pw = Pl + wave*16*200;

  for (int rb = wave; rb < 12; rb += 4){
    const int q0 = rb*16;
    const int qrow = q0 + lo;
    bf16x8 qa[2];
    #pragma unroll
    for (int kk=0;kk<2;++kk){
      u16x8 val = {0,0,0,0,0,0,0,0};
      if (qrow < NN) val = *reinterpret_cast<const u16x8*>(Qg + base + (size_t)qrow*DKk + kk*32 + hi*8);
      qa[kk] = as_bf(val);
    }
    f32x4 s[12];
    #pragma unroll
    for (int c=0;c<12;++c){
      f32x4 a = f32x4{0.f,0.f,0.f,0.f};
      #pragma unroll
      for (int kk=0;kk<2;++kk){
        bf16x8 kb = *reinterpret_cast<const bf16x8*>(&Kb[(c*16+lo)*72 + kk*32 + hi*8]);
        a = __builtin_amdgcn_mfma_f32_16x16x32_bf16(qa[kk], kb, a, 0,0,0);
      }
      s[c] = a;
    }
    const float* brow = biasA + ((size_t)g*NPAD + q0 + hi*4)*NPAD + lo;
    #pragma unroll
    for (int r=0;r<4;++r)
      #pragma unroll
      for (int c=0;c<12;++c)
        s[c][r] += brow[r*NPAD + c*16];
    float inv[4];
    #pragma unroll
    for (int r=0;r<4;++r){
      float m = s[0][r];
      #pragma unroll
      for (int c=1;c<12;++c) m = fmaxf(m, s[c][r]);
      #pragma unroll
      for (int off=1; off<16; off<<=1) m = fmaxf(m, __shfl_xor(m, off, 64));
      float t = 0.f;
      #pragma unroll
      for (int c=0;c<12;++c){ float e = __expf(s[c][r] - m); s[c][r] = e; t += e; }
      #pragma unroll
      for (int off=1; off<16; off<<=1) t += __shfl_xor(t, off, 64);
      inv[r] = 1.0f / t;
    }
    #pragma unroll
    for (int c=0;c<12;++c)
      #pragma unroll
      for (int r=0;r<4;++r)
        pw[(hi*4+r)*200 + c*16 + lo] = f2bf(s[c][r] * inv[r]);
    asm volatile("s_waitcnt lgkmcnt(0)" ::: "memory");
    __builtin_amdgcn_sched_barrier(0);
    bf16x8 pa[6];
    #pragma unroll
    for (int c6=0;c6<6;++c6)
      pa[c6] = *reinterpret_cast<const bf16x8*>(&pw[lo*200 + c6*32 + hi*8]);
    #pragma unroll
    for (int dt=0;dt<4;++dt){
      f32x4 a = f32x4{0.f,0.f,0.f,0.f};
      #pragma unroll
      for (int c6=0;c6<6;++c6){
        bf16x8 vb = *reinterpret_cast<const bf16x8*>(&Vt[(dt*16+lo)*200 + c6*32 + hi*8]);
        a = __builtin_amdgcn_mfma_f32_16x16x32_bf16(pa[c6], vb, a, 0,0,0);
      }
      #pragma unroll
      for (int r=0;r<4;++r){
        int q = q0 + hi*4 + r;
        if (q < NN)
          ctx[((size_t)b*NN + q)*DD + h*DKk + dt*16 + lo] = f2bf(a[r]);
      }
    }
  }
}

// ---------------- LayerNorm over D=512, one wave per row ----------------
template<int OUTF32>
__global__ __launch_bounds__(256) void ln_kernel(
    const u16* __restrict__ in, const float* __restrict__ gamma,
    const float* __restrict__ beta, void* __restrict__ outp)
{
  const int row = blockIdx.x*4 + (threadIdx.x >> 6);
  const int lane = threadIdx.x & 63;
  u16x8 rv = *reinterpret_cast<const u16x8*>(in + (size_t)row*512 + lane*8);
  float x[8]; float s = 0.f, s2 = 0.f;
  #pragma unroll
  for (int i=0;i<8;++i){ x[i] = bf2f(rv[i]); s += x[i]; s2 += x[i]*x[i]; }
  #pragma unroll
  for (int off=32; off>=1; off>>=1){ s += __shfl_xor(s, off, 64); s2 += __shfl_xor(s2, off, 64); }
  const float mu = s * (1.f/512.f);
  const float var = s2 * (1.f/512.f) - mu*mu;
  const float rstd = rsqrtf(var + 1e-5f);
  float4 ga = *reinterpret_cast<const float4*>(gamma + lane*8);
  float4 gb = *reinterpret_cast<const float4*>(gamma + lane*8 + 4);
  float4 ba = *reinterpret_cast<const float4*>(beta + lane*8);
  float4 bb = *reinterpret_cast<const float4*>(beta + lane*8 + 4);
  float gg[8] = {ga.x,ga.y,ga.z,ga.w,gb.x,gb.y,gb.z,gb.w};
  float bt[8] = {ba.x,ba.y,ba.z,ba.w,bb.x,bb.y,bb.z,bb.w};
  if constexpr (OUTF32){
    float o[8];
    #pragma unroll
    for (int i=0;i<8;++i) o[i] = (x[i]-mu)*rstd*gg[i] + bt[i];
    float4* op = reinterpret_cast<float4*>((float*)outp + (size_t)row*512 + lane*8);
    op[0] = make_float4(o[0],o[1],o[2],o[3]);
    op[1] = make_float4(o[4],o[5],o[6],o[7]);
  } else {
    u16x8 o;
    #pragma unroll
    for (int i=0;i<8;++i) o[i] = f2bf((x[i]-mu)*rstd*gg[i] + bt[i]);
    *reinterpret_cast<u16x8*>((u16*)outp + (size_t)row*512 + lane*8) = o;
  }
}

// ---------------- launch ----------------
// ws map (total 196,384,768 B) — same as r4-r7:
//   [0        ..  2097152) w1_b     [2097152 ..  4194304) w2_b
//   [4194304  ..  5767168) wqkv     [5767168 ..  6291456) wo_b
//   [6291456  ..  6586368) biasA    [6586368 ..  6592512) bqkv
//   [6592512  .. 54040576) xb  : x bf16 -> ctx
//   [54040576 ..101488640) qbuf: Q -> r1
//   [101488640..148936704) kbuf: K -> h
//   [148936704..196384768) vbuf: V -> s2
//   ffbuf = ws+4194304: 91-tile chunk x 2048 cols = 95,420,416 B, ends 99,614,720 < kbuf
extern "C" void kernel_launch(void* const* d_in, const int* in_sizes, int n_in,
                              void* d_out, int out_size, void* d_ws, size_t ws_size,
                              hipStream_t stream)
{
  if (ws_size < WS_NEEDED) return;

  const float* x   = (const float*)d_in[0];
  const int*   mask= (const int*)  d_in[1];
  const float* Wq  = (const float*)d_in[2];
  const float* bq  = (const float*)d_in[3];
  const float* Wk  = (const float*)d_in[4];
  const float* bk  = (const float*)d_in[5];
  const float* Wv  = (const float*)d_in[6];
  const float* bv  = (const float*)d_in[7];
  const float* Wo  = (const float*)d_in[8];
  const float* bo  = (const float*)d_in[9];
  const float* w1  = (const float*)d_in[10];
  const float* b1  = (const float*)d_in[11];
  const float* w2  = (const float*)d_in[12];
  const float* b2  = (const float*)d_in[13];
  const float* g1  = (const float*)d_in[14];
  const float* be1 = (const float*)d_in[15];
  const float* g2  = (const float*)d_in[16];
  const float* be2 = (const float*)d_in[17];

  char* ws = (char*)d_ws;
  u16*   w1_b  = (u16*)  (ws + 0);
  u16*   w2_b  = (u16*)  (ws + 2097152);
  u16*   wqkv  = (u16*)  (ws + 4194304);
  u16*   wo_b  = (u16*)  (ws + 5767168);
  float* biasA = (float*)(ws + 6291456);
  float* bqkv  = (float*)(ws + 6586368);
  u16*   xb    = (u16*)  (ws + 6592512);
  u16*   qbuf  = (u16*)  (ws + 54040576);
  u16*   kbuf  = qbuf + QKV_ELEMS;
  u16*   vbuf  = qbuf + 2*QKV_ELEMS;
  u16*   ffbuf = (u16*)  (ws + 4194304);

  // one fused prep launch
  prep_kernel<<<13157, 256, 0, stream>>>(x, Wq, Wk, Wv, Wo, w1, w2, bq, bk, bv,
                                         mask, xb, wqkv, wo_b, w1_b, w2_b, biasA, bqkv);

  // QKV projection (scatter to [B,H,N,64] bf16, Q scaled by 1/8)
  gemmR<0><<<dim3(6,181), 512, 0, stream>>>(xb, wqkv, 512, 1536, 512, 512,
                                            bqkv, qbuf, nullptr, nullptr);
  // fused segment attention -> ctx (xb region)
  attn_kernel<<<2048, 256, 0, stream>>>(qbuf, kbuf, vbuf, biasA, xb);
  // Wo projection + bo + x residual -> r1 (qbuf)
  gemmR<1><<<dim3(2,181), 512, 0, stream>>>(xb, wo_b, 512, 512, 512, 512,
                                            bo, qbuf, x, nullptr);
  // LN1 -> h (kbuf)
  ln_kernel<0><<<11584, 256, 0, stream>>>(qbuf, g1, be1, kbuf);
  // FFN split-M: chunk0 = 91 tiles (rows 0..23295), chunk1 = 90 tiles
  {
    const size_t ro = (size_t)23296 * 512;
    // FF1 c0: h x w1 + relu -> ffbuf [23296 x 2048]
    gemmR<2><<<dim3(8,91), 512, 0, stream>>>(kbuf, w1_b, 512, 2048, 512, 512,
                                             b1, ffbuf, nullptr, nullptr);
    // FF2 c0: ffbuf x w2 + b2 + h -> s2
    gemmR<5><<<dim3(2,91), 512, 0, stream>>>(ffbuf, w2_b, 2048, 512, 2048, 2048,
                                             b2, vbuf, nullptr, kbuf);
    // FF1 c1
    gemmR<2><<<dim3(8,90), 512, 0, stream>>>(kbuf + ro, w1_b, 512, 2048, 512, 512,
                                             b1, ffbuf, nullptr, nullptr);
    // FF2 c1
    gemmR<5><<<dim3(2,90), 512, 0, stream>>>(ffbuf, w2_b, 2048, 512, 2048, 2048,
                                             b2, vbuf + ro, nullptr, kbuf + ro);
  }
  // LN2 -> d_out (fp32)
  ln_kernel<1><<<11584, 256, 0, stream>>>(vbuf, g2, be2, d_out);
}

// Round 10
// 532.752 us; speedup vs baseline: 1.1247x; 1.0063x over previous
//
#include <hip/hip_runtime.h>
#include <math.h>

typedef unsigned short u16;
typedef unsigned int u32;
typedef short bf16x8 __attribute__((ext_vector_type(8)));
typedef unsigned short u16x8 __attribute__((ext_vector_type(8)));
typedef float f32x4 __attribute__((ext_vector_type(4)));

#define DEV static __device__ __forceinline__

#define BB 256
#define NN 181
#define DD 512
#define HH 8
#define DKk 64
#define NPAD 192
#define MTOT (BB*NN)          // 46336
#define QKV_ELEMS (23724032u) // B*H*N*64
#define WS_NEEDED 196384768ull
#define BSTR 136              // bounce row stride (u16)

DEV u16 f2bf(float f){
  u32 u = __float_as_uint(f);
  u32 r = (u + 0x7FFFu + ((u >> 16) & 1u)) >> 16;
  return (u16)r;
}
DEV float bf2f(u16 h){ return __uint_as_float(((u32)h) << 16); }
DEV bf16x8 as_bf(u16x8 v){ return __builtin_bit_cast(bf16x8, v); }

DEV void gl_lds16(const u16* g, u16* l){
  __builtin_amdgcn_global_load_lds(
      (const __attribute__((address_space(1))) unsigned int*)g,
      (__attribute__((address_space(3))) unsigned int*)l, 16, 0, 0);
}

// ---------------- unified prep: casts + bias table + bias concat ----------------
DEV void cast8(const float* __restrict__ src, u16* __restrict__ dst, int u){
  const float4* p = reinterpret_cast<const float4*>(src + (size_t)u*8);
  float4 a = p[0], b = p[1];
  u16x8 o;
  o[0]=f2bf(a.x); o[1]=f2bf(a.y); o[2]=f2bf(a.z); o[3]=f2bf(a.w);
  o[4]=f2bf(b.x); o[5]=f2bf(b.y); o[6]=f2bf(b.z); o[7]=f2bf(b.w);
  *reinterpret_cast<u16x8*>(dst + (size_t)u*8) = o;
}

#define SEG_X  2965504
#define SEG_Q  2998272
#define SEG_K  3031040
#define SEG_V  3063808
#define SEG_O  3096576
#define SEG_W1 3227648
#define SEG_W2 3358720
#define SEG_BI 3367936
#define SEG_BC 3368128

__global__ __launch_bounds__(256) void prep_kernel(
    const float* __restrict__ x,  const float* __restrict__ Wq,
    const float* __restrict__ Wk, const float* __restrict__ Wv,
    const float* __restrict__ Wo, const float* __restrict__ w1,
    const float* __restrict__ w2, const float* __restrict__ bq,
    const float* __restrict__ bk, const float* __restrict__ bv,
    const int* __restrict__ mask,
    u16* __restrict__ xb, u16* __restrict__ wqkv, u16* __restrict__ wo_b,
    u16* __restrict__ w1_b, u16* __restrict__ w2_b,
    float* __restrict__ biasA, float* __restrict__ bqkv)
{
  int u = blockIdx.x*256 + threadIdx.x;
  if (u < SEG_X)  { cast8(x,  xb,            u);          return; }
  if (u < SEG_Q)  { cast8(Wq, wqkv,          u - SEG_X);  return; }
  if (u < SEG_K)  { cast8(Wk, wqkv + 262144, u - SEG_Q);  return; }
  if (u < SEG_V)  { cast8(Wv, wqkv + 524288, u - SEG_K);  return; }
  if (u < SEG_O)  { cast8(Wo, wo_b,          u - SEG_V);  return; }
  if (u < SEG_W1) { cast8(w1, w1_b,          u - SEG_O);  return; }
  if (u < SEG_W2) { cast8(w2, w2_b,          u - SEG_W1); return; }
  if (u < SEG_BI) {
    int base = (u - SEG_W2)*8;
    #pragma unroll
    for (int j=0;j<8;++j){
      int idx = base + j;
      int g = idx / (NPAD*NPAD);
      int rem = idx % (NPAD*NPAD);
      int q = rem / NPAD, k = rem % NPAD;
      float v;
      if (k >= NN) v = -INFINITY;
      else if (q >= NN) v = 0.f;
      else {
        bool qv = q < 121, kv = k < 121;
        bool allowed = (g == 0) ? (qv != kv) : (qv == kv);
        if (!allowed) v = -INFINITY;
        else {
          int mb = (g == 0 && !qv) ? mask[k*NN + q] : mask[q*NN + k];
          v = mb ? -1e9f : 0.f;
        }
      }
      biasA[idx] = v;
    }
    return;
  }
  if (u < SEG_BC) {
    int base = (u - SEG_BI)*8;
    #pragma unroll
    for (int j=0;j<8;++j){
      int e = base + j;
      bqkv[e] = (e < 512) ? bq[e] : (e < 1024) ? bk[e-512] : bv[e-1024];
    }
    return;
  }
}

// ========== 128x128xBK64 GEMM (r5-verified K-loop), 2 blocks/CU, bounce epi ==========
// 8 waves (4M x 2N), one compute phase per K-tile, 2-tile-ahead prefetch,
// counted vmcnt(4), XCD bijective remap. LDS 64KB staging unioned with the
// 128x136 bounce tile. EPI 0: QKV scatter (+0.125 Q); 1: +bias + f32 residual
// (readback); 2: +bias+relu; 5: +bias + bf16 residual (readback).
#define STAGE(BUF, KT) do { int kt_=(KT); if (kt_>=ntiles) kt_=0; \
    const u16* a_ = stA + (size_t)kt_*64; \
    const u16* b_ = stB + (size_t)kt_*64; \
    gl_lds16(a_,      &ldsA[BUF][0][wave*512]); \
    gl_lds16(a_ + 32, &ldsA[BUF][1][wave*512]); \
    gl_lds16(b_,      &ldsB[BUF][0][wave*512]); \
    gl_lds16(b_ + 32, &ldsB[BUF][1][wave*512]); \
  } while(0)

#define SGB __builtin_amdgcn_sched_barrier(0)

template<int EPI>
__global__ __launch_bounds__(512, 4) void gemmT(
    const u16* __restrict__ A, const u16* __restrict__ Bw,
    int K, int N, int lda, int ldb,
    const float* __restrict__ bias,
    u16* __restrict__ outb,
    const float* __restrict__ resf,
    const u16* __restrict__ resb)
{
  __shared__ u16 ldsAll[32768];   // 64 KiB: staging / epilogue bounce
  u16 (*ldsA)[2][4096] = reinterpret_cast<u16(*)[2][4096]>(ldsAll);
  u16 (*ldsB)[2][4096] = reinterpret_cast<u16(*)[2][4096]>(ldsAll + 16384);
  const int tid = threadIdx.x, lane = tid & 63, wave = tid >> 6;
  const int lo = lane & 15, hi = lane >> 4;
  const int wm = wave >> 1, wn = wave & 1;

  // m204 bijective XCD remap, nt-fastest ids
  const int nwg = gridDim.x * gridDim.y;
  const int bid = blockIdx.x + gridDim.x * blockIdx.y;
  const int q8 = nwg >> 3, r8 = nwg & 7;
  const int xcd = bid & 7, j8 = bid >> 3;
  const int wgid = (xcd < r8 ? xcd*(q8+1) : r8*(q8+1) + (xcd-r8)*q8) + j8;
  const int ntb = wgid % gridDim.x, mt = wgid / gridDim.x;
  const int ntiles = K >> 6;

  // staging source (inverse subtile swizzle; dest linear per-wave slot) — verified
  const int pr = (wave << 4) | ((tid >> 2) & 15);
  const int pc = ((tid & 3) * 8) ^ (((tid >> 5) & 1) << 4);
  const u16* stA = A  + (size_t)(mt*128  + pr) * lda + pc;
  const u16* stB = Bw + (size_t)(ntb*128 + pr) * ldb + pc;
  // swizzled fragment-read bases (elements) — verified
  const int swz = (hi*8) ^ ((lo & 8) << 1);
  const int aRd = wm*1024 + lo*32 + swz;
  const int bRd = wn*2048 + lo*32 + swz;

  f32x4 acc[2][4];
  #pragma unroll
  for (int m=0;m<2;++m)
    #pragma unroll
    for (int n=0;n<4;++n) acc[m][n] = f32x4{0.f,0.f,0.f,0.f};

  // prologue: stage tile0 -> buf0, tile1 -> buf1; wait tile0 (oldest 4 of 8)
  STAGE(0, 0);
  STAGE(1, 1);
  asm volatile("s_waitcnt vmcnt(4)" ::: "memory");
  SGB;
  __builtin_amdgcn_s_barrier();
  SGB;

  #pragma unroll 2
  for (int kt = 0; kt < ntiles; ++kt){
    const int cb = kt & 1;
    bf16x8 af[2][2], bg[4][2];
    #pragma unroll
    for (int k_=0;k_<2;++k_){
      const u16* ah = &ldsA[cb][k_][0];
      const u16* bh = &ldsB[cb][k_][0];
      #pragma unroll
      for (int m_=0;m_<2;++m_)
        af[m_][k_] = *reinterpret_cast<const bf16x8*>(ah + aRd + m_*512);
      #pragma unroll
      for (int n_=0;n_<4;++n_)
        bg[n_][k_] = *reinterpret_cast<const bf16x8*>(bh + bRd + n_*512);
    }
    asm volatile("s_waitcnt lgkmcnt(0)" ::: "memory");
    SGB;
    __builtin_amdgcn_s_barrier();            // all waves done reading buf cb
    SGB;
    STAGE(cb, kt + 2);                       // overwrite buf cb with tile kt+2
    asm volatile("s_waitcnt vmcnt(4)" ::: "memory");  // tile kt+1 landed (mine)
    SGB;
    __builtin_amdgcn_s_barrier();            // tile kt+1 landed for all waves
    SGB;
    __builtin_amdgcn_s_setprio(1);
    #pragma unroll
    for (int m_=0;m_<2;++m_)
      #pragma unroll
      for (int n_=0;n_<4;++n_)
        #pragma unroll
        for (int k_=0;k_<2;++k_)
          acc[m_][n_] = __builtin_amdgcn_mfma_f32_16x16x32_bf16(
              af[m_][k_], bg[n_][k_], acc[m_][n_], 0,0,0);
    __builtin_amdgcn_s_setprio(0);
    SGB;
  }

  // ---------------- LDS-bounce epilogue ----------------
  asm volatile("s_waitcnt vmcnt(0)" ::: "memory");   // drain staging queue
  SGB;
  __builtin_amdgcn_s_barrier();                      // all waves drained
  SGB;

  float bv[4];
  #pragma unroll
  for (int n=0;n<4;++n) bv[n] = bias[ntb*128 + wn*64 + n*16 + lo];

  // write phase: bias (+scale/relu); residuals deferred to readback
  #pragma unroll
  for (int m=0;m<2;++m){
    #pragma unroll
    for (int rg=0;rg<4;++rg){
      const int trow = wm*32 + m*16 + hi*4 + rg;
      #pragma unroll
      for (int n=0;n<4;++n){
        const int tcol = wn*64 + n*16 + lo;
        float v = acc[m][n][rg] + bv[n];
        if constexpr (EPI == 0){
          if (((ntb*128 + tcol) >> 9) == 0) v *= 0.125f;   // Q scale
        } else if constexpr (EPI == 2){
          v = fmaxf(v, 0.f);
        }
        ldsAll[trow*BSTR + tcol] = f2bf(v);
      }
    }
  }
  __syncthreads();

  // readback: 4 passes; 16B/lane coalesced stores (+ coalesced residual add)
  const int rchunk = lane & 15;
  #pragma unroll
  for (int p=0;p<4;++p){
    const int trow = wave*16 + p*4 + (lane >> 4);
    const int grow = mt*128 + trow;
    const int gcol = ntb*128 + rchunk*8;
    u16x8 v = *reinterpret_cast<const u16x8*>(&ldsAll[trow*BSTR + rchunk*8]);
    if constexpr (EPI == 1){
      const float4* rp = reinterpret_cast<const float4*>(resf + (size_t)grow*N + gcol);
      float4 ra = rp[0], rb2 = rp[1];
      float rr[8] = {ra.x,ra.y,ra.z,ra.w,rb2.x,rb2.y,rb2.z,rb2.w};
      #pragma unroll
      for (int i=0;i<8;++i) v[i] = f2bf(bf2f(v[i]) + rr[i]);
    } else if constexpr (EPI == 5){
      u16x8 rv = *reinterpret_cast<const u16x8*>(resb + (size_t)grow*N + gcol);
      #pragma unroll
      for (int i=0;i<8;++i) v[i] = f2bf(bf2f(v[i]) + bf2f(rv[i]));
    }
    if constexpr (EPI == 0){
      const int bi = grow / NN, ni = grow - bi*NN;
      const int which = gcol >> 9, hh = (gcol >> 6) & 7, d = gcol & 63;
      *reinterpret_cast<u16x8*>(outb + (size_t)which*QKV_ELEMS +
          (((size_t)bi*HH + hh)*NN + ni)*DKk + d) = v;
    } else {
      *reinterpret_cast<u16x8*>(outb + (size_t)grow*N + gcol) = v;
    }
  }
}

// ---------------- fused segment attention (unchanged, verified r2-r8) ----------------
__global__ __launch_bounds__(256) void attn_kernel(
    const u16* __restrict__ Qg, const u16* __restrict__ Kg, const u16* __restrict__ Vg,
    const float* __restrict__ biasA, u16* __restrict__ ctx)
{
  __shared__ u16 Kb[NPAD*72];
  __shared__ u16 Vt[64*200];
  __shared__ u16 Pl[4*16*200];
  const int tid = threadIdx.x, lane = tid & 63, wave = tid >> 6;
  const int lo = lane & 15, hi = lane >> 4;
  const int bh = blockIdx.x;
  const int h = bh & 7, g = h >> 2, b = bh >> 3;
  const size_t base = (size_t)bh * NN * DKk;

  #pragma unroll
  for (int it=0; it<6; ++it){
    int row = it*32 + (tid >> 3);
    int cb = (tid & 7)*8;
    u16x8 val = {0,0,0,0,0,0,0,0};
    if (row < NN) val = *reinterpret_cast<const u16x8*>(Kg + base + (size_t)row*DKk + cb);
    *reinterpret_cast<u16x8*>(&Kb[row*72 + cb]) = val;
  }
  #pragma unroll
  for (int it=0; it<6; ++it){
    int row = it*32 + (tid >> 3);
    int cb = (tid & 7)*8;
    u16x8 val = {0,0,0,0,0,0,0,0};
    if (row < NN) val = *reinterpret_cast<const u16x8*>(Vg + base + (size_t)row*DKk + cb);
    *reinterpret_cast<u16x8*>(&Pl[row*64 + cb]) = val;
  }
  __syncthreads();
  #pragma unroll
  for (int j=0;j<6;++j){
    int task = j*256 + tid;
    int d = task & 63;
    int nc = task >> 6;
    u16x8 tv;
    #pragma unroll
    for (int i=0;i<8;++i) tv[i] = Pl[(nc*8+i)*64 + d];
    *reinterpret_cast<u16x8*>(&Vt[d*200 + nc*8]) = tv;
  }
  __syncthreads();

  u16* pw = Pl + wave*16*200;

  for (int rb = wave; rb < 12; rb += 4){
    const int q0 = rb*16;
    const int qrow = q0 + lo;
    bf16x8 qa[2];
    #pragma unroll
    for (int kk=0;kk<2;++kk){
      u16x8 val = {0,0,0,0,0,0,0,0};
      if (qrow < NN) val = *reinterpret_cast<const u16x8*>(Qg + base + (size_t)qrow*DKk + kk*32 + hi*8);
      qa[kk] = as_bf(val);
    }
    f32x4 s[12];
    #pragma unroll
    for (int c=0;c<12;++c){
      f32x4 a = f32x4{0.f,0.f,0.f,0.f};
      #pragma unroll
      for (int kk=0;kk<2;++kk){
        bf16x8 kb = *reinterpret_cast<const bf16x8*>(&Kb[(c*16+lo)*72 + kk*32 + hi*8]);
        a = __builtin_amdgcn_mfma_f32_16x16x32_bf16(qa[kk], kb, a, 0,0,0);
      }
      s[c] = a;
    }
    const float* brow = biasA + ((size_t)g*NPAD + q0 + hi*4)*NPAD + lo;
    #pragma unroll
    for (int r=0;r<4;++r)
      #pragma unroll
      for (int c=0;c<12;++c)
        s[c][r] += brow[r*NPAD + c*16];
    float inv[4];
    #pragma unroll
    for (int r=0;r<4;++r){
      float m = s[0][r];
      #pragma unroll
      for (int c=1;c<12;++c) m = fmaxf(m, s[c][r]);
      #pragma unroll
      for (int off=1; off<16; off<<=1) m = fmaxf(m, __shfl_xor(m, off, 64));
      float t = 0.f;
      #pragma unroll
      for (int c=0;c<12;++c){ float e = __expf(s[c][r] - m); s[c][r] = e; t += e; }
      #pragma unroll
      for (int off=1; off<16; off<<=1) t += __shfl_xor(t, off, 64);
      inv[r] = 1.0f / t;
    }
    #pragma unroll
    for (int c=0;c<12;++c)
      #pragma unroll
      for (int r=0;r<4;++r)
        pw[(hi*4+r)*200 + c*16 + lo] = f2bf(s[c][r] * inv[r]);
    asm volatile("s_waitcnt lgkmcnt(0)" ::: "memory");
    __builtin_amdgcn_sched_barrier(0);
    bf16x8 pa[6];
    #pragma unroll
    for (int c6=0;c6<6;++c6)
      pa[c6] = *reinterpret_cast<const bf16x8*>(&pw[lo*200 + c6*32 + hi*8]);
    #pragma unroll
    for (int dt=0;dt<4;++dt){
      f32x4 a = f32x4{0.f,0.f,0.f,0.f};
      #pragma unroll
      for (int c6=0;c6<6;++c6){
        bf16x8 vb = *reinterpret_cast<const bf16x8*>(&Vt[(dt*16+lo)*200 + c6*32 + hi*8]);
        a = __builtin_amdgcn_mfma_f32_16x16x32_bf16(pa[c6], vb, a, 0,0,0);
      }
      #pragma unroll
      for (int r=0;r<4;++r){
        int q = q0 + hi*4 + r;
        if (q < NN)
          ctx[((size_t)b*NN + q)*DD + h*DKk + dt*16 + lo] = f2bf(a[r]);
      }
    }
  }
}

// ---------------- LayerNorm over D=512, one wave per row ----------------
template<int OUTF32>
__global__ __launch_bounds__(256) void ln_kernel(
    const u16* __restrict__ in, const float* __restrict__ gamma,
    const float* __restrict__ beta, void* __restrict__ outp)
{
  const int row = blockIdx.x*4 + (threadIdx.x >> 6);
  const int lane = threadIdx.x & 63;
  u16x8 rv = *reinterpret_cast<const u16x8*>(in + (size_t)row*512 + lane*8);
  float x[8]; float s = 0.f, s2 = 0.f;
  #pragma unroll
  for (int i=0;i<8;++i){ x[i] = bf2f(rv[i]); s += x[i]; s2 += x[i]*x[i]; }
  #pragma unroll
  for (int off=32; off>=1; off>>=1){ s += __shfl_xor(s, off, 64); s2 += __shfl_xor(s2, off, 64); }
  const float mu = s * (1.f/512.f);
  const float var = s2 * (1.f/512.f) - mu*mu;
  const float rstd = rsqrtf(var + 1e-5f);
  float4 ga = *reinterpret_cast<const float4*>(gamma + lane*8);
  float4 gb = *reinterpret_cast<const float4*>(gamma + lane*8 + 4);
  float4 ba = *reinterpret_cast<const float4*>(beta + lane*8);
  float4 bb = *reinterpret_cast<const float4*>(beta + lane*8 + 4);
  float gg[8] = {ga.x,ga.y,ga.z,ga.w,gb.x,gb.y,gb.z,gb.w};
  float bt[8] = {ba.x,ba.y,ba.z,ba.w,bb.x,bb.y,bb.z,bb.w};
  if constexpr (OUTF32){
    float o[8];
    #pragma unroll
    for (int i=0;i<8;++i) o[i] = (x[i]-mu)*rstd*gg[i] + bt[i];
    float4* op = reinterpret_cast<float4*>((float*)outp + (size_t)row*512 + lane*8);
    op[0] = make_float4(o[0],o[1],o[2],o[3]);
    op[1] = make_float4(o[4],o[5],o[6],o[7]);
  } else {
    u16x8 o;
    #pragma unroll
    for (int i=0;i<8;++i) o[i] = f2bf((x[i]-mu)*rstd*gg[i] + bt[i]);
    *reinterpret_cast<u16x8*>((u16*)outp + (size_t)row*512 + lane*8) = o;
  }
}

// ---------------- launch ----------------
// ws map (total 196,384,768 B) — r2-r8 verified layout:
//   [0        ..  2097152) w1_b     [2097152 ..  4194304) w2_b
//   [4194304  ..  5767168) wqkv     [5767168 ..  6291456) wo_b
//   [6291456  ..  6586368) biasA    [6586368 ..  6592512) bqkv
//   [6592512  .. 54040576) xb : x bf16 -> ctx (attn overwrites; x f32 is the
//                                              Wo residual, read from d_in)
//   [54040576 ..101488640) qbuf: Q -> r1
//   [101488640..148936704) kbuf: K -> h
//   [148936704..196384768) vbuf: V -> s2
//   ffbuf = ws+4194304: FF1 chunk 23168x2048x2B = 94,896,128 -> ends 99,090,432
//           < kbuf (101,488,640); wqkv/wo_b/biasA/bqkv/xb/qbuf all dead by FF1
extern "C" void kernel_launch(void* const* d_in, const int* in_sizes, int n_in,
                              void* d_out, int out_size, void* d_ws, size_t ws_size,
                              hipStream_t stream)
{
  if (ws_size < WS_NEEDED) return;

  const float* x   = (const float*)d_in[0];
  const int*   mask= (const int*)  d_in[1];
  const float* Wq  = (const float*)d_in[2];
  const float* bq  = (const float*)d_in[3];
  const float* Wk  = (const float*)d_in[4];
  const float* bk  = (const float*)d_in[5];
  const float* Wv  = (const float*)d_in[6];
  const float* bv  = (const float*)d_in[7];
  const float* Wo  = (const float*)d_in[8];
  const float* bo  = (const float*)d_in[9];
  const float* w1  = (const float*)d_in[10];
  const float* b1  = (const float*)d_in[11];
  const float* w2  = (const float*)d_in[12];
  const float* b2  = (const float*)d_in[13];
  const float* g1  = (const float*)d_in[14];
  const float* be1 = (const float*)d_in[15];
  const float* g2  = (const float*)d_in[16];
  const float* be2 = (const float*)d_in[17];

  char* ws = (char*)d_ws;
  u16*   w1_b  = (u16*)  (ws + 0);
  u16*   w2_b  = (u16*)  (ws + 2097152);
  u16*   wqkv  = (u16*)  (ws + 4194304);
  u16*   wo_b  = (u16*)  (ws + 5767168);
  float* biasA = (float*)(ws + 6291456);
  float* bqkv  = (float*)(ws + 6586368);
  u16*   xb    = (u16*)  (ws + 6592512);
  u16*   qbuf  = (u16*)  (ws + 54040576);
  u16*   kbuf  = qbuf + QKV_ELEMS;
  u16*   vbuf  = qbuf + 2*QKV_ELEMS;
  u16*   ffbuf = (u16*)  (ws + 4194304);

  // one fused prep launch
  prep_kernel<<<13157, 256, 0, stream>>>(x, Wq, Wk, Wv, Wo, w1, w2, bq, bk, bv,
                                         mask, xb, wqkv, wo_b, w1_b, w2_b, biasA, bqkv);

  // QKV projection (scatter to [B,H,N,64] bf16, Q scaled by 1/8)
  gemmT<0><<<dim3(12,362), 512, 0, stream>>>(xb, wqkv, 512, 1536, 512, 512,
                                             bqkv, qbuf, nullptr, nullptr);
  // fused segment attention -> ctx (overwrites xb; x f32 stays in d_in)
  attn_kernel<<<2048, 256, 0, stream>>>(qbuf, kbuf, vbuf, biasA, xb);
  // Wo projection + bo + x (f32) residual -> r1 (qbuf)
  gemmT<1><<<dim3(4,362), 512, 0, stream>>>(xb, wo_b, 512, 512, 512, 512,
                                            bo, qbuf, x, nullptr);
  // LN1 -> h (kbuf)
  ln_kernel<0><<<11584, 256, 0, stream>>>(qbuf, g1, be1, kbuf);
  // FFN split-M: 2 chunks of 181 tiles (23168 rows)
  {
    const size_t ro = (size_t)23168 * 512;
    gemmT<2><<<dim3(16,181), 512, 0, stream>>>(kbuf, w1_b, 512, 2048, 512, 512,
                                               b1, ffbuf, nullptr, nullptr);
    gemmT<5><<<dim3(4,181), 512, 0, stream>>>(ffbuf, w2_b, 2048, 512, 2048, 2048,
                                              b2, vbuf, nullptr, kbuf);
    gemmT<2><<<dim3(16,181), 512, 0, stream>>>(kbuf + ro, w1_b, 512, 2048, 512, 512,
                                               b1, ffbuf, nullptr, nullptr);
    gemmT<5><<<dim3(4,181), 512, 0, stream>>>(ffbuf, w2_b, 2048, 512, 2048, 2048,
                                              b2, vbuf + ro, nullptr, kbuf + ro);
  }
  // LN2 -> d_out (fp32)
  ln_kernel<1><<<11584, 256, 0, stream>>>(vbuf, g2, be2, d_out);
}

// Round 11
// 524.327 us; speedup vs baseline: 1.1428x; 1.0161x over previous
//
#include <hip/hip_runtime.h>
#include <math.h>

typedef unsigned short u16;
typedef unsigned int u32;
typedef short bf16x8 __attribute__((ext_vector_type(8)));
typedef unsigned short u16x8 __attribute__((ext_vector_type(8)));
typedef float f32x4 __attribute__((ext_vector_type(4)));

#define DEV static __device__ __forceinline__

#define BB 256
#define NN 181
#define DD 512
#define HH 8
#define DKk 64
#define NPAD 192
#define MTOT (BB*NN)          // 46336
#define QKV_ELEMS (23724032u) // B*H*N*64
#define WS_NEEDED 196384768ull
#define BSTR 136              // bounce row stride (u16)

DEV u16 f2bf(float f){
  u32 u = __float_as_uint(f);
  u32 r = (u + 0x7FFFu + ((u >> 16) & 1u)) >> 16;
  return (u16)r;
}
DEV float bf2f(u16 h){ return __uint_as_float(((u32)h) << 16); }
DEV bf16x8 as_bf(u16x8 v){ return __builtin_bit_cast(bf16x8, v); }

DEV void gl_lds16(const u16* g, u16* l){
  __builtin_amdgcn_global_load_lds(
      (const __attribute__((address_space(1))) unsigned int*)g,
      (__attribute__((address_space(3))) unsigned int*)l, 16, 0, 0);
}

// ---------------- unified prep: casts + bias table + bias concat ----------------
DEV void cast8(const float* __restrict__ src, u16* __restrict__ dst, int u){
  const float4* p = reinterpret_cast<const float4*>(src + (size_t)u*8);
  float4 a = p[0], b = p[1];
  u16x8 o;
  o[0]=f2bf(a.x); o[1]=f2bf(a.y); o[2]=f2bf(a.z); o[3]=f2bf(a.w);
  o[4]=f2bf(b.x); o[5]=f2bf(b.y); o[6]=f2bf(b.z); o[7]=f2bf(b.w);
  *reinterpret_cast<u16x8*>(dst + (size_t)u*8) = o;
}

#define SEG_X  2965504
#define SEG_Q  2998272
#define SEG_K  3031040
#define SEG_V  3063808
#define SEG_O  3096576
#define SEG_W1 3227648
#define SEG_W2 3358720
#define SEG_BI 3367936
#define SEG_BC 3368128

__global__ __launch_bounds__(256) void prep_kernel(
    const float* __restrict__ x,  const float* __restrict__ Wq,
    const float* __restrict__ Wk, const float* __restrict__ Wv,
    const float* __restrict__ Wo, const float* __restrict__ w1,
    const float* __restrict__ w2, const float* __restrict__ bq,
    const float* __restrict__ bk, const float* __restrict__ bv,
    const int* __restrict__ mask,
    u16* __restrict__ xb, u16* __restrict__ wqkv, u16* __restrict__ wo_b,
    u16* __restrict__ w1_b, u16* __restrict__ w2_b,
    float* __restrict__ biasA, float* __restrict__ bqkv)
{
  int u = blockIdx.x*256 + threadIdx.x;
  if (u < SEG_X)  { cast8(x,  xb,            u);          return; }
  if (u < SEG_Q)  { cast8(Wq, wqkv,          u - SEG_X);  return; }
  if (u < SEG_K)  { cast8(Wk, wqkv + 262144, u - SEG_Q);  return; }
  if (u < SEG_V)  { cast8(Wv, wqkv + 524288, u - SEG_K);  return; }
  if (u < SEG_O)  { cast8(Wo, wo_b,          u - SEG_V);  return; }
  if (u < SEG_W1) { cast8(w1, w1_b,          u - SEG_O);  return; }
  if (u < SEG_W2) { cast8(w2, w2_b,          u - SEG_W1); return; }
  if (u < SEG_BI) {
    int base = (u - SEG_W2)*8;
    #pragma unroll
    for (int j=0;j<8;++j){
      int idx = base + j;
      int g = idx / (NPAD*NPAD);
      int rem = idx % (NPAD*NPAD);
      int q = rem / NPAD, k = rem % NPAD;
      float v;
      if (k >= NN) v = -INFINITY;
      else if (q >= NN) v = 0.f;
      else {
        bool qv = q < 121, kv = k < 121;
        bool allowed = (g == 0) ? (qv != kv) : (qv == kv);
        if (!allowed) v = -INFINITY;
        else {
          int mb = (g == 0 && !qv) ? mask[k*NN + q] : mask[q*NN + k];
          v = mb ? -1e9f : 0.f;
        }
      }
      biasA[idx] = v;
    }
    return;
  }
  if (u < SEG_BC) {
    int base = (u - SEG_BI)*8;
    #pragma unroll
    for (int j=0;j<8;++j){
      int e = base + j;
      bqkv[e] = (e < 512) ? bq[e] : (e < 1024) ? bk[e-512] : bv[e-1024];
    }
    return;
  }
}

// ========== 128x128xBK64 GEMM, 4 waves (2M x 2N), per-wave 64x64, 2 blocks/CU ====
// Same verified skeleton as r10 (swizzle, vmcnt discipline, bounce epilogue),
// re-parameterized: 256 thr, per-wave tile 64x64 -> block LDS reads 64KB/K-tile
// (vs 96KB at 32x64 wave tiles). STAGE = 8 gl_lds -> counted vmcnt(8).
// EPI 0: QKV scatter (+0.125 Q); 1: +bias+f32 residual (readback);
// 2: +bias+relu; 5: +bias + bf16 residual (readback).
#define STAGE(BUF, KT) do { int kt_=(KT); if (kt_>=ntiles) kt_=0; \
    const u16* a_ = stA + (size_t)kt_*64; \
    const u16* b_ = stB + (size_t)kt_*64; \
    gl_lds16(a_,                       &ldsA[BUF][0][wave*512]); \
    gl_lds16(a_ + 32,                  &ldsA[BUF][1][wave*512]); \
    gl_lds16(a_ + (size_t)64*lda,      &ldsA[BUF][0][wave*512 + 2048]); \
    gl_lds16(a_ + (size_t)64*lda + 32, &ldsA[BUF][1][wave*512 + 2048]); \
    gl_lds16(b_,                       &ldsB[BUF][0][wave*512]); \
    gl_lds16(b_ + 32,                  &ldsB[BUF][1][wave*512]); \
    gl_lds16(b_ + (size_t)64*ldb,      &ldsB[BUF][0][wave*512 + 2048]); \
    gl_lds16(b_ + (size_t)64*ldb + 32, &ldsB[BUF][1][wave*512 + 2048]); \
  } while(0)

#define SGB __builtin_amdgcn_sched_barrier(0)

template<int EPI>
__global__ __launch_bounds__(256, 2) void gemmT(
    const u16* __restrict__ A, const u16* __restrict__ Bw,
    int K, int N, int lda, int ldb,
    const float* __restrict__ bias,
    u16* __restrict__ outb,
    const float* __restrict__ resf,
    const u16* __restrict__ resb)
{
  __shared__ u16 ldsAll[32768];   // 64 KiB: staging / epilogue bounce
  u16 (*ldsA)[2][4096] = reinterpret_cast<u16(*)[2][4096]>(ldsAll);
  u16 (*ldsB)[2][4096] = reinterpret_cast<u16(*)[2][4096]>(ldsAll + 16384);
  const int tid = threadIdx.x, lane = tid & 63, wave = tid >> 6;
  const int lo = lane & 15, hi = lane >> 4;
  const int wm = wave >> 1, wn = wave & 1;

  // m204 bijective XCD remap, nt-fastest ids
  const int nwg = gridDim.x * gridDim.y;
  const int bid = blockIdx.x + gridDim.x * blockIdx.y;
  const int q8 = nwg >> 3, r8 = nwg & 7;
  const int xcd = bid & 7, j8 = bid >> 3;
  const int wgid = (xcd < r8 ? xcd*(q8+1) : r8*(q8+1) + (xcd-r8)*q8) + j8;
  const int ntb = wgid % gridDim.x, mt = wgid / gridDim.x;
  const int ntiles = K >> 6;

  // staging source (inverse subtile swizzle; dest wave-uniform slot) — r10-derived:
  // row = tid>>2 (+64 second pass), k = (tid&3)*8 ^ ((row&8)?16:0); row&8 == tid bit5
  const int pr = tid >> 2;
  const int pc = ((tid & 3) * 8) ^ (((tid >> 5) & 1) << 4);
  const u16* stA = A  + (size_t)(mt*128  + pr) * lda + pc;
  const u16* stB = Bw + (size_t)(ntb*128 + pr) * ldb + pc;
  // swizzled fragment-read bases (elements within a [128][32] half)
  const int swz = (hi*8) ^ ((lo & 8) << 1);
  const int aRd = wm*2048 + lo*32 + swz;
  const int bRd = wn*2048 + lo*32 + swz;

  f32x4 acc[4][4];
  #pragma unroll
  for (int m=0;m<4;++m)
    #pragma unroll
    for (int n=0;n<4;++n) acc[m][n] = f32x4{0.f,0.f,0.f,0.f};

  // prologue: stage tile0 -> buf0, tile1 -> buf1; wait tile0 (oldest 8 of 16)
  STAGE(0, 0);
  STAGE(1, 1);
  asm volatile("s_waitcnt vmcnt(8)" ::: "memory");
  SGB;
  __builtin_amdgcn_s_barrier();
  SGB;

  #pragma unroll 2
  for (int kt = 0; kt < ntiles; ++kt){
    const int cb = kt & 1;
    bf16x8 af[4][2], bg[4][2];
    #pragma unroll
    for (int k_=0;k_<2;++k_){
      const u16* ah = &ldsA[cb][k_][0];
      const u16* bh = &ldsB[cb][k_][0];
      #pragma unroll
      for (int m_=0;m_<4;++m_)
        af[m_][k_] = *reinterpret_cast<const bf16x8*>(ah + aRd + m_*512);
      #pragma unroll
      for (int n_=0;n_<4;++n_)
        bg[n_][k_] = *reinterpret_cast<const bf16x8*>(bh + bRd + n_*512);
    }
    asm volatile("s_waitcnt lgkmcnt(0)" ::: "memory");
    SGB;
    __builtin_amdgcn_s_barrier();            // all waves done reading buf cb
    SGB;
    STAGE(cb, kt + 2);                       // overwrite buf cb with tile kt+2
    asm volatile("s_waitcnt vmcnt(8)" ::: "memory");  // tile kt+1 landed (mine)
    SGB;
    __builtin_amdgcn_s_barrier();            // tile kt+1 landed for all waves
    SGB;
    __builtin_amdgcn_s_setprio(1);
    #pragma unroll
    for (int m_=0;m_<4;++m_)
      #pragma unroll
      for (int n_=0;n_<4;++n_)
        #pragma unroll
        for (int k_=0;k_<2;++k_)
          acc[m_][n_] = __builtin_amdgcn_mfma_f32_16x16x32_bf16(
              af[m_][k_], bg[n_][k_], acc[m_][n_], 0,0,0);
    __builtin_amdgcn_s_setprio(0);
    SGB;
  }

  // ---------------- LDS-bounce epilogue ----------------
  asm volatile("s_waitcnt vmcnt(0)" ::: "memory");   // drain staging queue
  SGB;
  __builtin_amdgcn_s_barrier();                      // all waves drained
  SGB;

  float bv[4];
  #pragma unroll
  for (int n=0;n<4;++n) bv[n] = bias[ntb*128 + wn*64 + n*16 + lo];

  // write phase: bias (+scale/relu); residuals deferred to readback
  #pragma unroll
  for (int m=0;m<4;++m){
    #pragma unroll
    for (int rg=0;rg<4;++rg){
      const int trow = wm*64 + m*16 + hi*4 + rg;
      #pragma unroll
      for (int n=0;n<4;++n){
        const int tcol = wn*64 + n*16 + lo;
        float v = acc[m][n][rg] + bv[n];
        if constexpr (EPI == 0){
          if (((ntb*128 + tcol) >> 9) == 0) v *= 0.125f;   // Q scale
        } else if constexpr (EPI == 2){
          v = fmaxf(v, 0.f);
        }
        ldsAll[trow*BSTR + tcol] = f2bf(v);
      }
    }
  }
  __syncthreads();

  // readback: 8 passes; 16B/lane coalesced stores (+ coalesced residual add)
  const int rchunk = tid & 15;
  #pragma unroll
  for (int p=0;p<8;++p){
    const int trow = p*16 + (tid >> 4);
    const int grow = mt*128 + trow;
    const int gcol = ntb*128 + rchunk*8;
    u16x8 v = *reinterpret_cast<const u16x8*>(&ldsAll[trow*BSTR + rchunk*8]);
    if constexpr (EPI == 1){
      const float4* rp = reinterpret_cast<const float4*>(resf + (size_t)grow*N + gcol);
      float4 ra = rp[0], rb2 = rp[1];
      float rr[8] = {ra.x,ra.y,ra.z,ra.w,rb2.x,rb2.y,rb2.z,rb2.w};
      #pragma unroll
      for (int i=0;i<8;++i) v[i] = f2bf(bf2f(v[i]) + rr[i]);
    } else if constexpr (EPI == 5){
      u16x8 rv = *reinterpret_cast<const u16x8*>(resb + (size_t)grow*N + gcol);
      #pragma unroll
      for (int i=0;i<8;++i) v[i] = f2bf(bf2f(v[i]) + bf2f(rv[i]));
    }
    if constexpr (EPI == 0){
      const int bi = grow / NN, ni = grow - bi*NN;
      const int which = gcol >> 9, hh = (gcol >> 6) & 7, d = gcol & 63;
      *reinterpret_cast<u16x8*>(outb + (size_t)which*QKV_ELEMS +
          (((size_t)bi*HH + hh)*NN + ni)*DKk + d) = v;
    } else {
      *reinterpret_cast<u16x8*>(outb + (size_t)grow*N + gcol) = v;
    }
  }
}

// ---------------- fused segment attention (unchanged, verified r2-r10) ----------------
__global__ __launch_bounds__(256) void attn_kernel(
    const u16* __restrict__ Qg, const u16* __restrict__ Kg, const u16* __restrict__ Vg,
    const float* __restrict__ biasA, u16* __restrict__ ctx)
{
  __shared__ u16 Kb[NPAD*72];
  __shared__ u16 Vt[64*200];
  __shared__ u16 Pl[4*16*200];
  const int tid = threadIdx.x, lane = tid & 63, wave = tid >> 6;
  const int lo = lane & 15, hi = lane >> 4;
  const int bh = blockIdx.x;
  const int h = bh & 7, g = h >> 2, b = bh >> 3;
  const size_t base = (size_t)bh * NN * DKk;

  #pragma unroll
  for (int it=0; it<6; ++it){
    int row = it*32 + (tid >> 3);
    int cb = (tid & 7)*8;
    u16x8 val = {0,0,0,0,0,0,0,0};
    if (row < NN) val = *reinterpret_cast<const u16x8*>(Kg + base + (size_t)row*DKk + cb);
    *reinterpret_cast<u16x8*>(&Kb[row*72 + cb]) = val;
  }
  #pragma unroll
  for (int it=0; it<6; ++it){
    int row = it*32 + (tid >> 3);
    int cb = (tid & 7)*8;
    u16x8 val = {0,0,0,0,0,0,0,0};
    if (row < NN) val = *reinterpret_cast<const u16x8*>(Vg + base + (size_t)row*DKk + cb);
    *reinterpret_cast<u16x8*>(&Pl[row*64 + cb]) = val;
  }
  __syncthreads();
  #pragma unroll
  for (int j=0;j<6;++j){
    int task = j*256 + tid;
    int d = task & 63;
    int nc = task >> 6;
    u16x8 tv;
    #pragma unroll
    for (int i=0;i<8;++i) tv[i] = Pl[(nc*8+i)*64 + d];
    *reinterpret_cast<u16x8*>(&Vt[d*200 + nc*8]) = tv;
  }
  __syncthreads();

  u16* pw = Pl + wave*16*200;

  for (int rb = wave; rb < 12; rb += 4){
    const int q0 = rb*16;
    const int qrow = q0 + lo;
    bf16x8 qa[2];
    #pragma unroll
    for (int kk=0;kk<2;++kk){
      u16x8 val = {0,0,0,0,0,0,0,0};
      if (qrow < NN) val = *reinterpret_cast<const u16x8*>(Qg + base + (size_t)qrow*DKk + kk*32 + hi*8);
      qa[kk] = as_bf(val);
    }
    f32x4 s[12];
    #pragma unroll
    for (int c=0;c<12;++c){
      f32x4 a = f32x4{0.f,0.f,0.f,0.f};
      #pragma unroll
      for (int kk=0;kk<2;++kk){
        bf16x8 kb = *reinterpret_cast<const bf16x8*>(&Kb[(c*16+lo)*72 + kk*32 + hi*8]);
        a = __builtin_amdgcn_mfma_f32_16x16x32_bf16(qa[kk], kb, a, 0,0,0);
      }
      s[c] = a;
    }
    const float* brow = biasA + ((size_t)g*NPAD + q0 + hi*4)*NPAD + lo;
    #pragma unroll
    for (int r=0;r<4;++r)
      #pragma unroll
      for (int c=0;c<12;++c)
        s[c][r] += brow[r*NPAD + c*16];
    float inv[4];
    #pragma unroll
    for (int r=0;r<4;++r){
      float m = s[0][r];
      #pragma unroll
      for (int c=1;c<12;++c) m = fmaxf(m, s[c][r]);
      #pragma unroll
      for (int off=1; off<16; off<<=1) m = fmaxf(m, __shfl_xor(m, off, 64));
      float t = 0.f;
      #pragma unroll
      for (int c=0;c<12;++c){ float e = __expf(s[c][r] - m); s[c][r] = e; t += e; }
      #pragma unroll
      for (int off=1; off<16; off<<=1) t += __shfl_xor(t, off, 64);
      inv[r] = 1.0f / t;
    }
    #pragma unroll
    for (int c=0;c<12;++c)
      #pragma unroll
      for (int r=0;r<4;++r)
        pw[(hi*4+r)*200 + c*16 + lo] = f2bf(s[c][r] * inv[r]);
    asm volatile("s_waitcnt lgkmcnt(0)" ::: "memory");
    __builtin_amdgcn_sched_barrier(0);
    bf16x8 pa[6];
    #pragma unroll
    for (int c6=0;c6<6;++c6)
      pa[c6] = *reinterpret_cast<const bf16x8*>(&pw[lo*200 + c6*32 + hi*8]);
    #pragma unroll
    for (int dt=0;dt<4;++dt){
      f32x4 a = f32x4{0.f,0.f,0.f,0.f};
      #pragma unroll
      for (int c6=0;c6<6;++c6){
        bf16x8 vb = *reinterpret_cast<const bf16x8*>(&Vt[(dt*16+lo)*200 + c6*32 + hi*8]);
        a = __builtin_amdgcn_mfma_f32_16x16x32_bf16(pa[c6], vb, a, 0,0,0);
      }
      #pragma unroll
      for (int r=0;r<4;++r){
        int q = q0 + hi*4 + r;
        if (q < NN)
          ctx[((size_t)b*NN + q)*DD + h*DKk + dt*16 + lo] = f2bf(a[r]);
      }
    }
  }
}

// ---------------- LayerNorm over D=512, one wave per row ----------------
template<int OUTF32>
__global__ __launch_bounds__(256) void ln_kernel(
    const u16* __restrict__ in, const float* __restrict__ gamma,
    const float* __restrict__ beta, void* __restrict__ outp)
{
  const int row = blockIdx.x*4 + (threadIdx.x >> 6);
  const int lane = threadIdx.x & 63;
  u16x8 rv = *reinterpret_cast<const u16x8*>(in + (size_t)row*512 + lane*8);
  float x[8]; float s = 0.f, s2 = 0.f;
  #pragma unroll
  for (int i=0;i<8;++i){ x[i] = bf2f(rv[i]); s += x[i]; s2 += x[i]*x[i]; }
  #pragma unroll
  for (int off=32; off>=1; off>>=1){ s += __shfl_xor(s, off, 64); s2 += __shfl_xor(s2, off, 64); }
  const float mu = s * (1.f/512.f);
  const float var = s2 * (1.f/512.f) - mu*mu;
  const float rstd = rsqrtf(var + 1e-5f);
  float4 ga = *reinterpret_cast<const float4*>(gamma + lane*8);
  float4 gb = *reinterpret_cast<const float4*>(gamma + lane*8 + 4);
  float4 ba = *reinterpret_cast<const float4*>(beta + lane*8);
  float4 bb = *reinterpret_cast<const float4*>(beta + lane*8 + 4);
  float gg[8] = {ga.x,ga.y,ga.z,ga.w,gb.x,gb.y,gb.z,gb.w};
  float bt[8] = {ba.x,ba.y,ba.z,ba.w,bb.x,bb.y,bb.z,bb.w};
  if constexpr (OUTF32){
    float o[8];
    #pragma unroll
    for (int i=0;i<8;++i) o[i] = (x[i]-mu)*rstd*gg[i] + bt[i];
    float4* op = reinterpret_cast<float4*>((float*)outp + (size_t)row*512 + lane*8);
    op[0] = make_float4(o[0],o[1],o[2],o[3]);
    op[1] = make_float4(o[4],o[5],o[6],o[7]);
  } else {
    u16x8 o;
    #pragma unroll
    for (int i=0;i<8;++i) o[i] = f2bf((x[i]-mu)*rstd*gg[i] + bt[i]);
    *reinterpret_cast<u16x8*>((u16*)outp + (size_t)row*512 + lane*8) = o;
  }
}

// ---------------- launch ----------------
// ws map (total 196,384,768 B) — r2-r10 verified layout:
//   [0        ..  2097152) w1_b     [2097152 ..  4194304) w2_b
//   [4194304  ..  5767168) wqkv     [5767168 ..  6291456) wo_b
//   [6291456  ..  6586368) biasA    [6586368 ..  6592512) bqkv
//   [6592512  .. 54040576) xb : x bf16 -> ctx (x f32 residual read from d_in)
//   [54040576 ..101488640) qbuf: Q -> r1
//   [101488640..148936704) kbuf: K -> h
//   [148936704..196384768) vbuf: V -> s2
//   ffbuf = ws+4194304: FF1 chunk 23168x2048x2B ends 99,090,432 < kbuf
extern "C" void kernel_launch(void* const* d_in, const int* in_sizes, int n_in,
                              void* d_out, int out_size, void* d_ws, size_t ws_size,
                              hipStream_t stream)
{
  if (ws_size < WS_NEEDED) return;

  const float* x   = (const float*)d_in[0];
  const int*   mask= (const int*)  d_in[1];
  const float* Wq  = (const float*)d_in[2];
  const float* bq  = (const float*)d_in[3];
  const float* Wk  = (const float*)d_in[4];
  const float* bk  = (const float*)d_in[5];
  const float* Wv  = (const float*)d_in[6];
  const float* bv  = (const float*)d_in[7];
  const float* Wo  = (const float*)d_in[8];
  const float* bo  = (const float*)d_in[9];
  const float* w1  = (const float*)d_in[10];
  const float* b1  = (const float*)d_in[11];
  const float* w2  = (const float*)d_in[12];
  const float* b2  = (const float*)d_in[13];
  const float* g1  = (const float*)d_in[14];
  const float* be1 = (const float*)d_in[15];
  const float* g2  = (const float*)d_in[16];
  const float* be2 = (const float*)d_in[17];

  char* ws = (char*)d_ws;
  u16*   w1_b  = (u16*)  (ws + 0);
  u16*   w2_b  = (u16*)  (ws + 2097152);
  u16*   wqkv  = (u16*)  (ws + 4194304);
  u16*   wo_b  = (u16*)  (ws + 5767168);
  float* biasA = (float*)(ws + 6291456);
  float* bqkv  = (float*)(ws + 6586368);
  u16*   xb    = (u16*)  (ws + 6592512);
  u16*   qbuf  = (u16*)  (ws + 54040576);
  u16*   kbuf  = qbuf + QKV_ELEMS;
  u16*   vbuf  = qbuf + 2*QKV_ELEMS;
  u16*   ffbuf = (u16*)  (ws + 4194304);

  // one fused prep launch
  prep_kernel<<<13157, 256, 0, stream>>>(x, Wq, Wk, Wv, Wo, w1, w2, bq, bk, bv,
                                         mask, xb, wqkv, wo_b, w1_b, w2_b, biasA, bqkv);

  // QKV projection (scatter to [B,H,N,64] bf16, Q scaled by 1/8)
  gemmT<0><<<dim3(12,362), 256, 0, stream>>>(xb, wqkv, 512, 1536, 512, 512,
                                             bqkv, qbuf, nullptr, nullptr);
  // fused segment attention -> ctx (overwrites xb; x f32 stays in d_in)
  attn_kernel<<<2048, 256, 0, stream>>>(qbuf, kbuf, vbuf, biasA, xb);
  // Wo projection + bo + x (f32) residual -> r1 (qbuf)
  gemmT<1><<<dim3(4,362), 256, 0, stream>>>(xb, wo_b, 512, 512, 512, 512,
                                            bo, qbuf, x, nullptr);
  // LN1 -> h (kbuf)
  ln_kernel<0><<<11584, 256, 0, stream>>>(qbuf, g1, be1, kbuf);
  // FFN split-M: 2 chunks of 181 tiles (23168 rows)
  {
    const size_t ro = (size_t)23168 * 512;
    gemmT<2><<<dim3(16,181), 256, 0, stream>>>(kbuf, w1_b, 512, 2048, 512, 512,
                                               b1, ffbuf, nullptr, nullptr);
    gemmT<5><<<dim3(4,181), 256, 0, stream>>>(ffbuf, w2_b, 2048, 512, 2048, 2048,
                                              b2, vbuf, nullptr, kbuf);
    gemmT<2><<<dim3(16,181), 256, 0, stream>>>(kbuf + ro, w1_b, 512, 2048, 512, 512,
                                               b1, ffbuf, nullptr, nullptr);
    gemmT<5><<<dim3(4,181), 256, 0, stream>>>(ffbuf, w2_b, 2048, 512, 2048, 2048,
                                              b2, vbuf + ro, nullptr, kbuf + ro);
  }
  // LN2 -> d_out (fp32)
  ln_kernel<1><<<11584, 256, 0, stream>>>(vbuf, g2, be2, d_out);
}

// Round 12
// 518.185 us; speedup vs baseline: 1.1564x; 1.0119x over previous
//
#include <hip/hip_runtime.h>
#include <math.h>

typedef unsigned short u16;
typedef unsigned int u32;
typedef short bf16x8 __attribute__((ext_vector_type(8)));
typedef unsigned short u16x8 __attribute__((ext_vector_type(8)));
typedef float f32x4 __attribute__((ext_vector_type(4)));

#define DEV static __device__ __forceinline__

#define BB 256
#define NN 181
#define DD 512
#define HH 8
#define DKk 64
#define NPAD 192
#define MTOT (BB*NN)          // 46336
#define QKV_ELEMS (23724032u) // B*H*N*64
#define WS_NEEDED 196384768ull
#define BSTR 136              // gemmT bounce row stride (u16)
#define ESTR 264              // gemm8 bounce row stride (u16)

DEV u16 f2bf(float f){
  u32 u = __float_as_uint(f);
  u32 r = (u + 0x7FFFu + ((u >> 16) & 1u)) >> 16;
  return (u16)r;
}
DEV float bf2f(u16 h){ return __uint_as_float(((u32)h) << 16); }
DEV bf16x8 as_bf(u16x8 v){ return __builtin_bit_cast(bf16x8, v); }

DEV void gl_lds16(const u16* g, u16* l){
  __builtin_amdgcn_global_load_lds(
      (const __attribute__((address_space(1))) unsigned int*)g,
      (__attribute__((address_space(3))) unsigned int*)l, 16, 0, 0);
}

// ---------------- unified prep ----------------
DEV void cast8(const float* __restrict__ src, u16* __restrict__ dst, int u){
  const float4* p = reinterpret_cast<const float4*>(src + (size_t)u*8);
  float4 a = p[0], b = p[1];
  u16x8 o;
  o[0]=f2bf(a.x); o[1]=f2bf(a.y); o[2]=f2bf(a.z); o[3]=f2bf(a.w);
  o[4]=f2bf(b.x); o[5]=f2bf(b.y); o[6]=f2bf(b.z); o[7]=f2bf(b.w);
  *reinterpret_cast<u16x8*>(dst + (size_t)u*8) = o;
}

#define SEG_X  2965504
#define SEG_Q  2998272
#define SEG_K  3031040
#define SEG_V  3063808
#define SEG_O  3096576
#define SEG_W1 3227648
#define SEG_W2 3358720
#define SEG_BI 3367936
#define SEG_BC 3368128

__global__ __launch_bounds__(256) void prep_kernel(
    const float* __restrict__ x,  const float* __restrict__ Wq,
    const float* __restrict__ Wk, const float* __restrict__ Wv,
    const float* __restrict__ Wo, const float* __restrict__ w1,
    const float* __restrict__ w2, const float* __restrict__ bq,
    const float* __restrict__ bk, const float* __restrict__ bv,
    const int* __restrict__ mask,
    u16* __restrict__ xb, u16* __restrict__ wqkv, u16* __restrict__ wo_b,
    u16* __restrict__ w1_b, u16* __restrict__ w2_b,
    float* __restrict__ biasA, float* __restrict__ bqkv)
{
  int u = blockIdx.x*256 + threadIdx.x;
  if (u < SEG_X)  { cast8(x,  xb,            u);          return; }
  if (u < SEG_Q)  { cast8(Wq, wqkv,          u - SEG_X);  return; }
  if (u < SEG_K)  { cast8(Wk, wqkv + 262144, u - SEG_Q);  return; }
  if (u < SEG_V)  { cast8(Wv, wqkv + 524288, u - SEG_K);  return; }
  if (u < SEG_O)  { cast8(Wo, wo_b,          u - SEG_V);  return; }
  if (u < SEG_W1) { cast8(w1, w1_b,          u - SEG_O);  return; }
  if (u < SEG_W2) { cast8(w2, w2_b,          u - SEG_W1); return; }
  if (u < SEG_BI) {
    int base = (u - SEG_W2)*8;
    #pragma unroll
    for (int j=0;j<8;++j){
      int idx = base + j;
      int g = idx / (NPAD*NPAD);
      int rem = idx % (NPAD*NPAD);
      int q = rem / NPAD, k = rem % NPAD;
      float v;
      if (k >= NN) v = -INFINITY;
      else if (q >= NN) v = 0.f;
      else {
        bool qv = q < 121, kv = k < 121;
        bool allowed = (g == 0) ? (qv != kv) : (qv == kv);
        if (!allowed) v = -INFINITY;
        else {
          int mb = (g == 0 && !qv) ? mask[k*NN + q] : mask[q*NN + k];
          v = mb ? -1e9f : 0.f;
        }
      }
      biasA[idx] = v;
    }
    return;
  }
  if (u < SEG_BC) {
    int base = (u - SEG_BI)*8;
    #pragma unroll
    for (int j=0;j<8;++j){
      int e = base + j;
      bqkv[e] = (e < 512) ? bq[e] : (e < 1024) ? bk[e-512] : bv[e-1024];
    }
    return;
  }
}

#define SGB __builtin_amdgcn_sched_barrier(0)

// ========== gemm8: faithful m201 256x256 8-phase, zigzag operand-persistent ==========
// 512 thr = 8 waves (2M x 4N), per-wave 128x64, BK=64, 2 K-tiles/iter,
// 24 ds_read/wave/K-tile, distance-6 half-tile staging, vmcnt(6) @P4/P8,
// XCD bijective remap, bounce epilogue. EPI 0: QKV scatter; 2: +bias+relu.
#define RDA8(CB, MH) do{ \
    _Pragma("unroll") for(int m_=0;m_<4;++m_) \
      _Pragma("unroll") for(int k_=0;k_<2;++k_) \
        afx[m_][k_] = *reinterpret_cast<const bf16x8*>( \
            &ldsT[CB][0][MH][0] + aRdBase + m_*2048 + k_*512); \
  }while(0)
#define RDB4(CB, NH, BG) do{ \
    _Pragma("unroll") for(int n_=0;n_<2;++n_) \
      _Pragma("unroll") for(int k_=0;k_<2;++k_) \
        BG[n_][k_] = *reinterpret_cast<const bf16x8*>( \
            &ldsT[CB][1][NH][0] + bRdBase + n_*4096 + k_*512); \
  }while(0)
#define STG(SB, SO, SH, KT) do{ int kt_=(KT); if(kt_>=ntiles) kt_=0; \
    const int ld_ = (SO)==0? lda: ldb; \
    const u16* s_ = ((SO)==0? stA: stB) + (size_t)(SH)*128*ld_ + (size_t)kt_*64; \
    gl_lds16(s_, &ldsT[SB][SO][SH][wave*512]); \
    gl_lds16(s_ + (size_t)64*ld_, &ldsT[SB][SO][SH][wave*512+4096]); \
  }while(0)
#define BARS do{ SGB; __builtin_amdgcn_s_barrier(); SGB; }while(0)
#define MF16(MH, NH, BG) do{ __builtin_amdgcn_s_setprio(1); \
    _Pragma("unroll") for(int m_=0;m_<4;++m_) \
      _Pragma("unroll") for(int n_=0;n_<2;++n_) \
        _Pragma("unroll") for(int k_=0;k_<2;++k_) \
          acc[(MH)*4+m_][(NH)*2+n_] = __builtin_amdgcn_mfma_f32_16x16x32_bf16( \
              afx[m_][k_], BG[n_][k_], acc[(MH)*4+m_][(NH)*2+n_], 0,0,0); \
    __builtin_amdgcn_s_setprio(0); \
  }while(0)
#define VM6 asm volatile("s_waitcnt vmcnt(6)" ::: "memory")

template<int EPI>
__global__ __launch_bounds__(512, 2) void gemm8(
    const u16* __restrict__ A, const u16* __restrict__ Bw,
    int K, int N, int lda, int ldb,
    const float* __restrict__ bias,
    u16* __restrict__ outb)
{
  __shared__ u16 ldsAll8[65536];   // 128 KiB staging / bounce
  u16 (*ldsT)[2][2][8192] = reinterpret_cast<u16(*)[2][2][8192]>(ldsAll8);
  const int tid = threadIdx.x, lane = tid & 63, wave = tid >> 6;
  const int lo = lane & 15, hi = lane >> 4;
  const int wm = wave >> 2, wn = wave & 3;

  // m204 bijective XCD remap, nt-fastest ids
  const int nwg = gridDim.x * gridDim.y;
  const int bid = blockIdx.x + gridDim.x * blockIdx.y;
  const int q8 = nwg >> 3, r8 = nwg & 7;
  const int xcd = bid & 7, j8 = bid >> 3;
  const int wgid = (xcd < r8 ? xcd*(q8+1) : r8*(q8+1) + (xcd-r8)*q8) + j8;
  const int ntb = wgid % gridDim.x, mt = wgid / gridDim.x;
  const int ntiles = K >> 6, niter = ntiles >> 1;

  // staging source (inverse subtile swizzle; dest linear per-wave) — r3-verified
  const int pr = ((tid >> 7) << 4) | ((tid >> 2) & 15);
  const int pc = (((tid >> 6) & 1) << 5) | (((tid & 3) * 8) ^ (((tid >> 5) & 1) << 4));
  const u16* stA = A  + (size_t)(mt*256 + pr) * lda + pc;
  const u16* stB = Bw + (size_t)(ntb*256 + pr) * ldb + pc;
  // swizzled fragment-read bases — r3-verified
  const int swz = (hi*8) ^ ((lo & 8) << 1);
  const int aRdBase = wm*1024 + lo*32 + swz;
  const int bRdBase = wn*1024 + lo*32 + swz;

  f32x4 acc[8][4];
  #pragma unroll
  for (int f=0; f<8; ++f)
    #pragma unroll
    for (int n=0; n<4; ++n) acc[f][n] = f32x4{0.f,0.f,0.f,0.f};

  // prologue: t0 all 4 halves + t1 {A0,B0,B1} (14 loads); vmcnt(6) -> t0 landed
  STG(0,0,0, 0); STG(0,1,0, 0); STG(0,1,1, 0); STG(0,0,1, 0);
  STG(1,0,0, 1); STG(1,1,0, 1); STG(1,1,1, 1);
  VM6;
  BARS;

  for (int i = 0; i < niter; ++i){
    const int v1 = 2*i+1, u2 = 2*i+2, v2 = 2*i+3;
    bf16x8 afx[4][2], bg0[2][2], bg1[2][2];
    // P1 (u: 0,0)
    RDA8(0,0); RDB4(0,0,bg0); STG(1,0,1, v1);      BARS; MF16(0,0,bg0); BARS;
    // P2 (u: 0,1)
    RDB4(0,1,bg1);            STG(0,0,0, u2);      BARS; MF16(0,1,bg1); BARS;
    // P3 (u: 1,1)
    RDA8(0,1);                STG(0,1,0, u2);      BARS; MF16(1,1,bg1); BARS;
    // P4 (u: 1,0) — no reads; afx=A1(P3), bg0=B0(P1)
    STG(0,1,1, u2); VM6;                           BARS; MF16(1,0,bg0); BARS;
    // P5 (v: 0,0)
    RDA8(1,0); RDB4(1,0,bg0); STG(0,0,1, u2);      BARS; MF16(0,0,bg0); BARS;
    // P6 (v: 0,1)
    RDB4(1,1,bg1);            STG(1,0,0, v2);      BARS; MF16(0,1,bg1); BARS;
    // P7 (v: 1,1)
    RDA8(1,1);                STG(1,1,0, v2);      BARS; MF16(1,1,bg1); BARS;
    // P8 (v: 1,0)
    STG(1,1,1, v2); VM6;                           BARS; MF16(1,0,bg0); BARS;
  }
  asm volatile("s_waitcnt vmcnt(0)" ::: "memory");
  BARS;

  // bounce epilogue: 2 passes of 128 rows, [128][ESTR] tile, 16B/lane stores
  float bv[4];
  #pragma unroll
  for (int n=0; n<4; ++n) bv[n] = bias[ntb*256 + wn*16 + n*64 + lo];

  #pragma unroll
  for (int q=0; q<2; ++q){
    #pragma unroll
    for (int m_=0; m_<4; ++m_){
      const int f = q*4 + m_;
      #pragma unroll
      for (int rg=0; rg<4; ++rg){
        const int trow = wm*16 + m_*32 + hi*4 + rg;   // 0..127
        #pragma unroll
        for (int n=0; n<4; ++n){
          const int tcol = wn*16 + n*64 + lo;
          float v = acc[f][n][rg] + bv[n];
          if constexpr (EPI == 0){
            if (((ntb*256 + tcol) >> 9) == 0) v *= 0.125f;
          } else {
            v = fmaxf(v, 0.f);
          }
          ldsAll8[trow*ESTR + tcol] = f2bf(v);
        }
      }
    }
    __syncthreads();
    const int rchunk = tid & 31;
    #pragma unroll
    for (int p=0; p<8; ++p){
      const int row = p*16 + (tid >> 5);
      const int grow = mt*256 + q*128 + row;
      const int gcol = ntb*256 + rchunk*8;
      u16x8 v = *reinterpret_cast<const u16x8*>(&ldsAll8[row*ESTR + rchunk*8]);
      if constexpr (EPI == 0){
        const int bi = grow / NN, ni = grow - bi*NN;
        const int which = gcol >> 9, hh = (gcol >> 6) & 7, d = gcol & 63;
        *reinterpret_cast<u16x8*>(outb + (size_t)which*QKV_ELEMS +
            (((size_t)bi*HH + hh)*NN + ni)*DKk + d) = v;
      } else {
        *reinterpret_cast<u16x8*>(outb + (size_t)grow*N + gcol) = v;
      }
    }
    __syncthreads();
  }
}

// ========== gemmT 128x128 (r11-verified) for Wo / FF2 ==========
#define STAGE(BUF, KT) do { int kt_=(KT); if (kt_>=ntiles) kt_=0; \
    const u16* a_ = stA + (size_t)kt_*64; \
    const u16* b_ = stB + (size_t)kt_*64; \
    gl_lds16(a_,                       &ldsA[BUF][0][wave*512]); \
    gl_lds16(a_ + 32,                  &ldsA[BUF][1][wave*512]); \
    gl_lds16(a_ + (size_t)64*lda,      &ldsA[BUF][0][wave*512 + 2048]); \
    gl_lds16(a_ + (size_t)64*lda + 32, &ldsA[BUF][1][wave*512 + 2048]); \
    gl_lds16(b_,                       &ldsB[BUF][0][wave*512]); \
    gl_lds16(b_ + 32,                  &ldsB[BUF][1][wave*512]); \
    gl_lds16(b_ + (size_t)64*ldb,      &ldsB[BUF][0][wave*512 + 2048]); \
    gl_lds16(b_ + (size_t)64*ldb + 32, &ldsB[BUF][1][wave*512 + 2048]); \
  } while(0)

template<int EPI>
__global__ __launch_bounds__(256, 2) void gemmT(
    const u16* __restrict__ A, const u16* __restrict__ Bw,
    int K, int N, int lda, int ldb,
    const float* __restrict__ bias,
    u16* __restrict__ outb,
    const float* __restrict__ resf,
    const u16* __restrict__ resb)
{
  __shared__ u16 ldsAll[32768];
  u16 (*ldsA)[2][4096] = reinterpret_cast<u16(*)[2][4096]>(ldsAll);
  u16 (*ldsB)[2][4096] = reinterpret_cast<u16(*)[2][4096]>(ldsAll + 16384);
  const int tid = threadIdx.x, lane = tid & 63, wave = tid >> 6;
  const int lo = lane & 15, hi = lane >> 4;
  const int wm = wave >> 1, wn = wave & 1;

  const int nwg = gridDim.x * gridDim.y;
  const int bid = blockIdx.x + gridDim.x * blockIdx.y;
  const int q8 = nwg >> 3, r8 = nwg & 7;
  const int xcd = bid & 7, j8 = bid >> 3;
  const int wgid = (xcd < r8 ? xcd*(q8+1) : r8*(q8+1) + (xcd-r8)*q8) + j8;
  const int ntb = wgid % gridDim.x, mt = wgid / gridDim.x;
  const int ntiles = K >> 6;

  const int pr = tid >> 2;
  const int pc = ((tid & 3) * 8) ^ (((tid >> 5) & 1) << 4);
  const u16* stA = A  + (size_t)(mt*128  + pr) * lda + pc;
  const u16* stB = Bw + (size_t)(ntb*128 + pr) * ldb + pc;
  const int swz = (hi*8) ^ ((lo & 8) << 1);
  const int aRd = wm*2048 + lo*32 + swz;
  const int bRd = wn*2048 + lo*32 + swz;

  f32x4 acc[4][4];
  #pragma unroll
  for (int m=0;m<4;++m)
    #pragma unroll
    for (int n=0;n<4;++n) acc[m][n] = f32x4{0.f,0.f,0.f,0.f};

  STAGE(0, 0);
  STAGE(1, 1);
  asm volatile("s_waitcnt vmcnt(8)" ::: "memory");
  SGB;
  __builtin_amdgcn_s_barrier();
  SGB;

  #pragma unroll 2
  for (int kt = 0; kt < ntiles; ++kt){
    const int cb = kt & 1;
    bf16x8 af[4][2], bg[4][2];
    #pragma unroll
    for (int k_=0;k_<2;++k_){
      const u16* ah = &ldsA[cb][k_][0];
      const u16* bh = &ldsB[cb][k_][0];
      #pragma unroll
      for (int m_=0;m_<4;++m_)
        af[m_][k_] = *reinterpret_cast<const bf16x8*>(ah + aRd + m_*512);
      #pragma unroll
      for (int n_=0;n_<4;++n_)
        bg[n_][k_] = *reinterpret_cast<const bf16x8*>(bh + bRd + n_*512);
    }
    asm volatile("s_waitcnt lgkmcnt(0)" ::: "memory");
    SGB;
    __builtin_amdgcn_s_barrier();
    SGB;
    STAGE(cb, kt + 2);
    asm volatile("s_waitcnt vmcnt(8)" ::: "memory");
    SGB;
    __builtin_amdgcn_s_barrier();
    SGB;
    __builtin_amdgcn_s_setprio(1);
    #pragma unroll
    for (int m_=0;m_<4;++m_)
      #pragma unroll
      for (int n_=0;n_<4;++n_)
        #pragma unroll
        for (int k_=0;k_<2;++k_)
          acc[m_][n_] = __builtin_amdgcn_mfma_f32_16x16x32_bf16(
              af[m_][k_], bg[n_][k_], acc[m_][n_], 0,0,0);
    __builtin_amdgcn_s_setprio(0);
    SGB;
  }

  asm volatile("s_waitcnt vmcnt(0)" ::: "memory");
  SGB;
  __builtin_amdgcn_s_barrier();
  SGB;

  float bv[4];
  #pragma unroll
  for (int n=0;n<4;++n) bv[n] = bias[ntb*128 + wn*64 + n*16 + lo];

  #pragma unroll
  for (int m=0;m<4;++m){
    #pragma unroll
    for (int rg=0;rg<4;++rg){
      const int trow = wm*64 + m*16 + hi*4 + rg;
      #pragma unroll
      for (int n=0;n<4;++n){
        const int tcol = wn*64 + n*16 + lo;
        float v = acc[m][n][rg] + bv[n];
        if constexpr (EPI == 2){
          v = fmaxf(v, 0.f);
        }
        ldsAll[trow*BSTR + tcol] = f2bf(v);
      }
    }
  }
  __syncthreads();

  const int rchunk = tid & 15;
  #pragma unroll
  for (int p=0;p<8;++p){
    const int trow = p*16 + (tid >> 4);
    const int grow = mt*128 + trow;
    const int gcol = ntb*128 + rchunk*8;
    u16x8 v = *reinterpret_cast<const u16x8*>(&ldsAll[trow*BSTR + rchunk*8]);
    if constexpr (EPI == 1){
      const float4* rp = reinterpret_cast<const float4*>(resf + (size_t)grow*N + gcol);
      float4 ra = rp[0], rb2 = rp[1];
      float rr[8] = {ra.x,ra.y,ra.z,ra.w,rb2.x,rb2.y,rb2.z,rb2.w};
      #pragma unroll
      for (int i=0;i<8;++i) v[i] = f2bf(bf2f(v[i]) + rr[i]);
    } else if constexpr (EPI == 5){
      u16x8 rv = *reinterpret_cast<const u16x8*>(resb + (size_t)grow*N + gcol);
      #pragma unroll
      for (int i=0;i<8;++i) v[i] = f2bf(bf2f(v[i]) + bf2f(rv[i]));
    }
    *reinterpret_cast<u16x8*>(outb + (size_t)grow*N + gcol) = v;
  }
}

// ---------------- fused segment attention (unchanged, verified r2-r11) ----------------
__global__ __launch_bounds__(256) void attn_kernel(
    const u16* __restrict__ Qg, const u16* __restrict__ Kg, const u16* __restrict__ Vg,
    const float* __restrict__ biasA, u16* __restrict__ ctx)
{
  __shared__ u16 Kb[NPAD*72];
  __shared__ u16 Vt[64*200];
  __shared__ u16 Pl[4*16*200];
  const int tid = threadIdx.x, lane = tid & 63, wave = tid >> 6;
  const int lo = lane & 15, hi = lane >> 4;
  const int bh = blockIdx.x;
  const int h = bh & 7, g = h >> 2, b = bh >> 3;
  const size_t base = (size_t)bh * NN * DKk;

  #pragma unroll
  for (int it=0; it<6; ++it){
    int row = it*32 + (tid >> 3);
    int cb = (tid & 7)*8;
    u16x8 val = {0,0,0,0,0,0,0,0};
    if (row < NN) val = *reinterpret_cast<const u16x8*>(Kg + base + (size_t)row*DKk + cb);
    *reinterpret_cast<u16x8*>(&Kb[row*72 + cb]) = val;
  }
  #pragma unroll
  for (int it=0; it<6; ++it){
    int row = it*32 + (tid >> 3);
    int cb = (tid & 7)*8;
    u16x8 val = {0,0,0,0,0,0,0,0};
    if (row < NN) val = *reinterpret_cast<const u16x8*>(Vg + base + (size_t)row*DKk + cb);
    *reinterpret_cast<u16x8*>(&Pl[row*64 + cb]) = val;
  }
  __syncthreads();
  #pragma unroll
  for (int j=0;j<6;++j){
    int task = j*256 + tid;
    int d = task & 63;
    int nc = task >> 6;
    u16x8 tv;
    #pragma unroll
    for (int i=0;i<8;++i) tv[i] = Pl[(nc*8+i)*64 + d];
    *reinterpret_cast<u16x8*>(&Vt[d*200 + nc*8]) = tv;
  }
  __syncthreads();

  u16* pw = Pl + wave*16*200;

  for (int rb = wave; rb < 12; rb += 4){
    const int q0 = rb*16;
    const int qrow = q0 + lo;
    bf16x8 qa[2];
    #pragma unroll
    for (int kk=0;kk<2;++kk){
      u16x8 val = {0,0,0,0,0,0,0,0};
      if (qrow < NN) val = *reinterpret_cast<const u16x8*>(Qg + base + (size_t)qrow*DKk + kk*32 + hi*8);
      qa[kk] = as_bf(val);
    }
    f32x4 s[12];
    #pragma unroll
    for (int c=0;c<12;++c){
      f32x4 a = f32x4{0.f,0.f,0.f,0.f};
      #pragma unroll
      for (int kk=0;kk<2;++kk){
        bf16x8 kb = *reinterpret_cast<const bf16x8*>(&Kb[(c*16+lo)*72 + kk*32 + hi*8]);
        a = __builtin_amdgcn_mfma_f32_16x16x32_bf16(qa[kk], kb, a, 0,0,0);
      }
      s[c] = a;
    }
    const float* brow = biasA + ((size_t)g*NPAD + q0 + hi*4)*NPAD + lo;
    #pragma unroll
    for (int r=0;r<4;++r)
      #pragma unroll
      for (int c=0;c<12;++c)
        s[c][r] += brow[r*NPAD + c*16];
    float inv[4];
    #pragma unroll
    for (int r=0;r<4;++r){
      float m = s[0][r];
      #pragma unroll
      for (int c=1;c<12;++c) m = fmaxf(m, s[c][r]);
      #pragma unroll
      for (int off=1; off<16; off<<=1) m = fmaxf(m, __shfl_xor(m, off, 64));
      float t = 0.f;
      #pragma unroll
      for (int c=0;c<12;++c){ float e = __expf(s[c][r] - m); s[c][r] = e; t += e; }
      #pragma unroll
      for (int off=1; off<16; off<<=1) t += __shfl_xor(t, off, 64);
      inv[r] = 1.0f / t;
    }
    #pragma unroll
    for (int c=0;c<12;++c)
      #pragma unroll
      for (int r=0;r<4;++r)
        pw[(hi*4+r)*200 + c*16 + lo] = f2bf(s[c][r] * inv[r]);
    asm volatile("s_waitcnt lgkmcnt(0)" ::: "memory");
    __builtin_amdgcn_sched_barrier(0);
    bf16x8 pa[6];
    #pragma unroll
    for (int c6=0;c6<6;++c6)
      pa[c6] = *reinterpret_cast<const bf16x8*>(&pw[lo*200 + c6*32 + hi*8]);
    #pragma unroll
    for (int dt=0;dt<4;++dt){
      f32x4 a = f32x4{0.f,0.f,0.f,0.f};
      #pragma unroll
      for (int c6=0;c6<6;++c6){
        bf16x8 vb = *reinterpret_cast<const bf16x8*>(&Vt[(dt*16+lo)*200 + c6*32 + hi*8]);
        a = __builtin_amdgcn_mfma_f32_16x16x32_bf16(pa[c6], vb, a, 0,0,0);
      }
      #pragma unroll
      for (int r=0;r<4;++r){
        int q = q0 + hi*4 + r;
        if (q < NN)
          ctx[((size_t)b*NN + q)*DD + h*DKk + dt*16 + lo] = f2bf(a[r]);
      }
    }
  }
}

// ---------------- LayerNorm over D=512, one wave per row ----------------
template<int OUTF32>
__global__ __launch_bounds__(256) void ln_kernel(
    const u16* __restrict__ in, const float* __restrict__ gamma,
    const float* __restrict__ beta, void* __restrict__ outp)
{
  const int row = blockIdx.x*4 + (threadIdx.x >> 6);
  const int lane = threadIdx.x & 63;
  u16x8 rv = *reinterpret_cast<const u16x8*>(in + (size_t)row*512 + lane*8);
  float x[8]; float s = 0.f, s2 = 0.f;
  #pragma unroll
  for (int i=0;i<8;++i){ x[i] = bf2f(rv[i]); s += x[i]; s2 += x[i]*x[i]; }
  #pragma unroll
  for (int off=32; off>=1; off>>=1){ s += __shfl_xor(s, off, 64); s2 += __shfl_xor(s2, off, 64); }
  const float mu = s * (1.f/512.f);
  const float var = s2 * (1.f/512.f) - mu*mu;
  const float rstd = rsqrtf(var + 1e-5f);
  float4 ga = *reinterpret_cast<const float4*>(gamma + lane*8);
  float4 gb = *reinterpret_cast<const float4*>(gamma + lane*8 + 4);
  float4 ba = *reinterpret_cast<const float4*>(beta + lane*8);
  float4 bb = *reinterpret_cast<const float4*>(beta + lane*8 + 4);
  float gg[8] = {ga.x,ga.y,ga.z,ga.w,gb.x,gb.y,gb.z,gb.w};
  float bt[8] = {ba.x,ba.y,ba.z,ba.w,bb.x,bb.y,bb.z,bb.w};
  if constexpr (OUTF32){
    float o[8];
    #pragma unroll
    for (int i=0;i<8;++i) o[i] = (x[i]-mu)*rstd*gg[i] + bt[i];
    float4* op = reinterpret_cast<float4*>((float*)outp + (size_t)row*512 + lane*8);
    op[0] = make_float4(o[0],o[1],o[2],o[3]);
    op[1] = make_float4(o[4],o[5],o[6],o[7]);
  } else {
    u16x8 o;
    #pragma unroll
    for (int i=0;i<8;++i) o[i] = f2bf((x[i]-mu)*rstd*gg[i] + bt[i]);
    *reinterpret_cast<u16x8*>((u16*)outp + (size_t)row*512 + lane*8) = o;
  }
}

// ---------------- launch ----------------
// ws map (total 196,384,768 B) — r2-r11 verified layout:
//   [0        ..  2097152) w1_b     [2097152 ..  4194304) w2_b
//   [4194304  ..  5767168) wqkv     [5767168 ..  6291456) wo_b
//   [6291456  ..  6586368) biasA    [6586368 ..  6592512) bqkv
//   [6592512  .. 54040576) xb : x bf16 -> ctx (x f32 residual read from d_in)
//   [54040576 ..101488640) qbuf: Q -> r1
//   [101488640..148936704) kbuf: K -> h
//   [148936704..196384768) vbuf: V -> s2
//   ffbuf = ws+4194304: FF1 chunk 23296x2048x2B = 95,420,416 ends 99,614,720 < kbuf
extern "C" void kernel_launch(void* const* d_in, const int* in_sizes, int n_in,
                              void* d_out, int out_size, void* d_ws, size_t ws_size,
                              hipStream_t stream)
{
  if (ws_size < WS_NEEDED) return;

  const float* x   = (const float*)d_in[0];
  const int*   mask= (const int*)  d_in[1];
  const float* Wq  = (const float*)d_in[2];
  const float* bq  = (const float*)d_in[3];
  const float* Wk  = (const float*)d_in[4];
  const float* bk  = (const float*)d_in[5];
  const float* Wv  = (const float*)d_in[6];
  const float* bv  = (const float*)d_in[7];
  const float* Wo  = (const float*)d_in[8];
  const float* bo  = (const float*)d_in[9];
  const float* w1  = (const float*)d_in[10];
  const float* b1  = (const float*)d_in[11];
  const float* w2  = (const float*)d_in[12];
  const float* b2  = (const float*)d_in[13];
  const float* g1  = (const float*)d_in[14];
  const float* be1 = (const float*)d_in[15];
  const float* g2  = (const float*)d_in[16];
  const float* be2 = (const float*)d_in[17];

  char* ws = (char*)d_ws;
  u16*   w1_b  = (u16*)  (ws + 0);
  u16*   w2_b  = (u16*)  (ws + 2097152);
  u16*   wqkv  = (u16*)  (ws + 4194304);
  u16*   wo_b  = (u16*)  (ws + 5767168);
  float* biasA = (float*)(ws + 6291456);
  float* bqkv  = (float*)(ws + 6586368);
  u16*   xb    = (u16*)  (ws + 6592512);
  u16*   qbuf  = (u16*)  (ws + 54040576);
  u16*   kbuf  = qbuf + QKV_ELEMS;
  u16*   vbuf  = qbuf + 2*QKV_ELEMS;
  u16*   ffbuf = (u16*)  (ws + 4194304);

  // one fused prep launch
  prep_kernel<<<13157, 256, 0, stream>>>(x, Wq, Wk, Wv, Wo, w1, w2, bq, bk, bv,
                                         mask, xb, wqkv, wo_b, w1_b, w2_b, biasA, bqkv);

  // QKV projection (m201-style 256^2 8-phase; scatter to [B,H,N,64], Q*0.125)
  gemm8<0><<<dim3(6,181), 512, 0, stream>>>(xb, wqkv, 512, 1536, 512, 512,
                                            bqkv, qbuf);
  // fused segment attention -> ctx (overwrites xb; x f32 stays in d_in)
  attn_kernel<<<2048, 256, 0, stream>>>(qbuf, kbuf, vbuf, biasA, xb);
  // Wo projection + bo + x (f32) residual -> r1 (qbuf)
  gemmT<1><<<dim3(4,362), 256, 0, stream>>>(xb, wo_b, 512, 512, 512, 512,
                                            bo, qbuf, x, nullptr);
  // LN1 -> h (kbuf)
  ln_kernel<0><<<11584, 256, 0, stream>>>(qbuf, g1, be1, kbuf);
  // FFN split-M: chunks of 91 + 90 tiles of 256 rows
  {
    const size_t ro = (size_t)23296 * 512;
    gemm8<2><<<dim3(8,91), 512, 0, stream>>>(kbuf, w1_b, 512, 2048, 512, 512,
                                             b1, ffbuf);
    gemmT<5><<<dim3(4,182), 256, 0, stream>>>(ffbuf, w2_b, 2048, 512, 2048, 2048,
                                              b2, vbuf, nullptr, kbuf);
    gemm8<2><<<dim3(8,90), 512, 0, stream>>>(kbuf + ro, w1_b, 512, 2048, 512, 512,
                                             b1, ffbuf);
    gemmT<5><<<dim3(4,180), 256, 0, stream>>>(ffbuf, w2_b, 2048, 512, 2048, 2048,
                                              b2, vbuf + ro, nullptr, kbuf + ro);
  }
  // LN2 -> d_out (fp32)
  ln_kernel<1><<<11584, 256, 0, stream>>>(vbuf, g2, be2, d_out);
}